// Round 7
// baseline (384.050 us; speedup 1.0000x reference)
//
#include <hip/hip_runtime.h>
#include <hip/hip_bf16.h>

#define NN 50000     // nodes
#define NR 4         // relations
#define NE 160000    // edges per relation
#define HD 128       // hidden dim
#define OD 100       // out dim
#define NQ 8192      // queries
#define NB_SCAN 196  // 196*256 >= NN

typedef __attribute__((ext_vector_type(8))) short bf16x8;
typedef __attribute__((ext_vector_type(4))) float f32x4;
typedef __attribute__((ext_vector_type(4))) int int4v;

static __device__ __forceinline__ unsigned short f2bf(float f) {
    union { float f; unsigned int u; } v; v.f = f;
    unsigned int u = v.u;
    unsigned int r = u + 0x7FFFu + ((u >> 16) & 1u);   // RNE
    return (unsigned short)(r >> 16);
}
static __device__ __forceinline__ float bflo(unsigned int v) {
    union { unsigned int u; float f; } x; x.u = v << 16; return x.f;
}
static __device__ __forceinline__ float bfhi(unsigned int v) {
    union { unsigned int u; float f; } x; x.u = v & 0xffff0000u; return x.f;
}

// ---------------- graph preprocessing ----------------

__global__ void zero_deg_kernel(int* __restrict__ deg) {
    int i = blockIdx.x * 256 + threadIdx.x;
    if (i < NR * NN) deg[i] = 0;
}

__global__ void count_deg_kernel(const int* __restrict__ edge_dst, int* __restrict__ deg) {
    int i = blockIdx.x * 256 + threadIdx.x;
    if (i < NR * NE) {
        int r = i / NE;
        atomicAdd(&deg[r * NN + edge_dst[i]], 1);
    }
}

__global__ __launch_bounds__(256) void scanA_kernel(const int* __restrict__ deg,
                                                    int* __restrict__ excl,
                                                    int* __restrict__ bsum) {
    const int r = blockIdx.x / NB_SCAN;
    const int b = blockIdx.x % NB_SCAN;
    const int tid = threadIdx.x;
    const int idx = b * 256 + tid;
    int v = (idx < NN) ? deg[r * NN + idx] : 0;
    __shared__ int buf[256];
    buf[tid] = v; __syncthreads();
    int sum = v;
    for (int off = 1; off < 256; off <<= 1) {
        int t = (tid >= off) ? buf[tid - off] : 0;
        __syncthreads();
        sum += t; buf[tid] = sum;
        __syncthreads();
    }
    if (idx < NN) excl[r * NN + idx] = sum - v;
    if (tid == 255) bsum[r * NB_SCAN + b] = sum;
}

__global__ __launch_bounds__(256) void scanB_kernel(int* __restrict__ bsum) {
    const int r = blockIdx.x;
    const int tid = threadIdx.x;
    int v = (tid < NB_SCAN) ? bsum[r * NB_SCAN + tid] : 0;
    __shared__ int buf[256];
    buf[tid] = v; __syncthreads();
    int sum = v;
    for (int off = 1; off < 256; off <<= 1) {
        int t = (tid >= off) ? buf[tid - off] : 0;
        __syncthreads();
        sum += t; buf[tid] = sum;
        __syncthreads();
    }
    if (tid < NB_SCAN) bsum[r * NB_SCAN + tid] = sum - v;
}

__global__ __launch_bounds__(256) void scanC_kernel(const int* __restrict__ excl,
                                                    const int* __restrict__ bsum,
                                                    int* __restrict__ row_start,
                                                    int* __restrict__ cursor) {
    const int r = blockIdx.x / NB_SCAN;
    const int b = blockIdx.x % NB_SCAN;
    const int idx = b * 256 + threadIdx.x;
    if (idx < NN) {
        int v = excl[r * NN + idx] + bsum[r * NB_SCAN + b];
        row_start[r * (NN + 1) + idx] = v;
        cursor[r * NN + idx] = v;
    }
    if (b == 0 && threadIdx.x == 0) row_start[r * (NN + 1) + NN] = NE;
}

__global__ void fill_csr_kernel(const int* __restrict__ edge_src,
                                const int* __restrict__ edge_dst,
                                int* __restrict__ cursor, int* __restrict__ csr_src) {
    int i = blockIdx.x * 256 + threadIdx.x;
    if (i < NR * NE) {
        int r = i / NE;
        int dst = edge_dst[i];
        int pos = atomicAdd(&cursor[r * NN + dst], 1);
        csr_src[r * NE + pos] = edge_src[i];
    }
}

// ---------------- weight / feature prep ----------------

__global__ void conv_feat_kernel(const float* __restrict__ f, unsigned short* __restrict__ h) {
    int i = (blockIdx.x * 256 + threadIdx.x) * 4;
    if (i < NN * HD) {
        h[i + 0] = f2bf(f[i + 0]);
        h[i + 1] = f2bf(f[i + 1]);
        h[i + 2] = f2bf(f[i + 2]);
        h[i + 3] = f2bf(f[i + 3]);
    }
}

// WtH [128 cols][640 k] bf16: k<128 -> Ws[k][c]; k=128+r*128+kk -> Wr[r][kk][c]
__global__ void prep_wh_kernel(const float* __restrict__ Ws, const float* __restrict__ Wr,
                               unsigned short* __restrict__ Wt) {
    int c = blockIdx.x;     // 128
    int k = threadIdx.x;    // 640
    float v;
    if (k < HD) v = Ws[k * HD + c];
    else {
        int r = (k - HD) >> 7, kk = (k - HD) & 127;
        v = Wr[(r * HD + kk) * HD + c];
    }
    Wt[c * (NR + 1) * HD + k] = f2bf(v);
}

// WtO [128 cols][640 k] bf16: cols >= 100 are zero
__global__ void prep_wo_kernel(const float* __restrict__ Ws, const float* __restrict__ Wr,
                               unsigned short* __restrict__ Wt) {
    int c = blockIdx.x;     // 128
    int k = threadIdx.x;    // 640
    float v = 0.0f;
    if (c < OD) {
        if (k < HD) v = Ws[k * OD + c];
        else {
            int r = (k - HD) >> 7, kk = (k - HD) & 127;
            v = Wr[(r * HD + kk) * OD + c];
        }
    }
    Wt[c * (NR + 1) * HD + k] = f2bf(v);
}

// ---------------- fused: deep-pipelined reg gather + GEMM ----------------
// Block = 512 thr (8 waves), 64 nodes. LDS = agg tile [64 rows][1024B bf16] = 64KB.
// Gather: wave w, lane-group g (16 lanes x 16B = full 256B h row) walks the
//   CONTIGUOUS CSR range of relation g over nodes [m0+8w, m0+8w+8): one
//   pipeline prologue per 8 nodes, srcs batched 4-per-dwordx4, values 8 deep
//   in flight, regs accumulate fp32, per-node emit = scale (1/deg from run
//   length) + pack + one swizzled ds_write_b128. No atomics.
// GEMM: [h | agg](64x640) @ Wt(128x640)^T. Wave (wm,wn) = 32 rows x 32 cols;
//   A k<128 direct from global h (L2-hot), k>=128 from swizzled LDS agg;
//   B direct from global Wt. 20 K-steps, 4 MFMA each, no barriers in loop.
// MODE 0: relu + bf16 out via LDS bounce. MODE 1: f32 out via LDS bounce.

#define CONSUME(Vi, OFS)                                                         \
    if (t + OFS < tend) {                                                        \
        while (t + OFS >= eb && cur < 7) EMIT();                                 \
        const unsigned int* vu = (const unsigned int*)&Vi;                       \
        a0 += bflo(vu[0]); a1 += bfhi(vu[0]);                                    \
        a2 += bflo(vu[1]); a3 += bfhi(vu[1]);                                    \
        a4 += bflo(vu[2]); a5 += bfhi(vu[2]);                                    \
        a6 += bflo(vu[3]); a7 += bfhi(vu[3]);                                    \
    }

template<int MODE>
__global__ __launch_bounds__(512, 2)
void fused_kernel(const unsigned short* __restrict__ h,
                  const unsigned short* __restrict__ Bt,
                  const int* __restrict__ row_start,
                  const int* __restrict__ csr_src,
                  void* __restrict__ outp, int M) {
    __shared__ __align__(16) char lds[65536];
    const int tid = threadIdx.x;
    const int m0 = blockIdx.x * 64;
    const int lane = tid & 63;
    const int w = tid >> 6;            // 0..7
    const int g = lane >> 4;           // relation
    const int li = lane & 15;

    // ---- gather ----
    {
        const int nodes0 = m0 + (w << 3);
        const int rsBase = g * (NN + 1);
        auto LB = [&](int i) {
            int n = nodes0 + i; if (n > NN) n = NN;
            return row_start[rsBase + n];
        };
        const int b0 = LB(0);
        int eb = LB(1);
        int e2 = LB(2), e3 = LB(3), e4 = LB(4), e5 = LB(5), e6 = LB(6), e7 = LB(7);
        int e8 = LB(8);
        const int tend = e8;

        const int* __restrict__ csr = csr_src + g * NE;
        const char* hp = (const char*)h + li * 16;

        int t = b0;
        int sb = t;
        int cur = 0;
        float a0 = 0.f, a1 = 0.f, a2 = 0.f, a3 = 0.f,
              a4 = 0.f, a5 = 0.f, a6 = 0.f, a7 = 0.f;

        auto EMIT = [&]() {
            const float inv = 1.0f / fmaxf((float)(eb - sb), 1.0f);
            unsigned int p0 = (unsigned int)f2bf(inv * a0) | ((unsigned int)f2bf(inv * a1) << 16);
            unsigned int p1 = (unsigned int)f2bf(inv * a2) | ((unsigned int)f2bf(inv * a3) << 16);
            unsigned int p2 = (unsigned int)f2bf(inv * a4) | ((unsigned int)f2bf(inv * a5) << 16);
            unsigned int p3 = (unsigned int)f2bf(inv * a6) | ((unsigned int)f2bf(inv * a7) << 16);
            const int row = (w << 3) + cur;
            *(int4v*)(lds + row * 1024 + ((g * 256 + li * 16) ^ ((row & 7) << 4))) =
                (int4v){(int)p0, (int)p1, (int)p2, (int)p3};
            a0 = a1 = a2 = a3 = a4 = a5 = a6 = a7 = 0.f;
            sb = eb;
            ++cur;
            eb = e2; e2 = e3; e3 = e4; e4 = e5; e5 = e6; e6 = e7; e7 = e8;
        };

        int4v S0 = {0,0,0,0}, S1 = {0,0,0,0}, S2 = {0,0,0,0};
        int4v V0, V1, V2, V3, W0, W1, W2, W3;
        if (t     < tend) S0 = *(const int4v*)(csr + t);
        if (t + 4 < tend) S1 = *(const int4v*)(csr + t + 4);
        if (t     < tend) V0 = *(const int4v*)(hp + S0[0] * 256);
        if (t + 1 < tend) V1 = *(const int4v*)(hp + S0[1] * 256);
        if (t + 2 < tend) V2 = *(const int4v*)(hp + S0[2] * 256);
        if (t + 3 < tend) V3 = *(const int4v*)(hp + S0[3] * 256);
        if (t + 4 < tend) W0 = *(const int4v*)(hp + S1[0] * 256);
        if (t + 5 < tend) W1 = *(const int4v*)(hp + S1[1] * 256);
        if (t + 6 < tend) W2 = *(const int4v*)(hp + S1[2] * 256);
        if (t + 7 < tend) W3 = *(const int4v*)(hp + S1[3] * 256);

        while (__any(t < tend)) {
            if (t + 8 < tend) S2 = *(const int4v*)(csr + t + 8);
            CONSUME(V0, 0) CONSUME(V1, 1) CONSUME(V2, 2) CONSUME(V3, 3)
            V0 = W0; V1 = W1; V2 = W2; V3 = W3;
            S0 = S1; S1 = S2;
            t += 4;
            if (t + 4 < tend) W0 = *(const int4v*)(hp + S1[0] * 256);
            if (t + 5 < tend) W1 = *(const int4v*)(hp + S1[1] * 256);
            if (t + 6 < tend) W2 = *(const int4v*)(hp + S1[2] * 256);
            if (t + 7 < tend) W3 = *(const int4v*)(hp + S1[3] * 256);
        }
        while (cur < 8) EMIT();
    }
    __syncthreads();

    // ---- GEMM: wave (wm,wn): rows wm*32..+32, cols wn*32..+32 ----
    const int wm = w >> 2;
    const int wn = w & 3;
    const int lr = lane & 15;
    const int lg = lane >> 4;
    const char* bB = (const char*)Bt;

    int arow[2];
#pragma unroll
    for (int mi = 0; mi < 2; mi++) {
        int rw = m0 + wm * 32 + mi * 16 + lr;
        if (rw >= M) rw = M - 1;
        arow[mi] = rw;
    }

    f32x4 acc[2][2];
#pragma unroll
    for (int mi = 0; mi < 2; mi++)
#pragma unroll
        for (int ni = 0; ni < 2; ni++) acc[mi][ni] = (f32x4){0.f, 0.f, 0.f, 0.f};

#pragma unroll
    for (int kb = 0; kb < 20; ++kb) {
        const int kByte = kb * 64 + lg * 16;
        bf16x8 af[2], bfr[2];
#pragma unroll
        for (int ni = 0; ni < 2; ni++)
            bfr[ni] = *(const bf16x8*)(bB + (wn * 32 + ni * 16 + lr) * 1280 + kByte);
        if (kb < 4) {
#pragma unroll
            for (int mi = 0; mi < 2; mi++)
                af[mi] = *(const bf16x8*)((const char*)h + arow[mi] * 256 + kByte);
        } else {
            const int kk = kByte - 256;
#pragma unroll
            for (int mi = 0; mi < 2; mi++) {
                const int row = wm * 32 + mi * 16 + lr;
                af[mi] = *(const bf16x8*)(lds + row * 1024 + (kk ^ ((row & 7) << 4)));
            }
        }
#pragma unroll
        for (int mi = 0; mi < 2; mi++)
#pragma unroll
            for (int ni = 0; ni < 2; ni++)
                acc[mi][ni] = __builtin_amdgcn_mfma_f32_16x16x32_bf16(af[mi], bfr[ni], acc[mi][ni], 0, 0, 0);
    }

    __syncthreads();                        // agg reads done; reuse LDS as bounce

    if (MODE == 0) {
        // relu -> bf16 tile [64][256B] = 16KB
#pragma unroll
        for (int mi = 0; mi < 2; mi++)
#pragma unroll
            for (int ni = 0; ni < 2; ni++) {
                const int col = wn * 32 + ni * 16 + lr;
#pragma unroll
                for (int j = 0; j < 4; j++) {
                    const int row = wm * 32 + mi * 16 + lg * 4 + j;
                    *(unsigned short*)(lds + row * 256 + col * 2) =
                        f2bf(fmaxf(acc[mi][ni][j], 0.f));
                }
            }
        __syncthreads();
        unsigned short* o = (unsigned short*)outp;
        const int row = tid >> 3, ob = (tid & 7) * 32;
        const int grow = m0 + row;
        if (grow < M) {
            *(int4v*)((char*)o + grow * 256 + ob) = *(const int4v*)(lds + row * 256 + ob);
            *(int4v*)((char*)o + grow * 256 + ob + 16) = *(const int4v*)(lds + row * 256 + ob + 16);
        }
    } else {
        // f32 tile [64][512B] = 32KB
#pragma unroll
        for (int mi = 0; mi < 2; mi++)
#pragma unroll
            for (int ni = 0; ni < 2; ni++) {
                const int col = wn * 32 + ni * 16 + lr;
#pragma unroll
                for (int j = 0; j < 4; j++) {
                    const int row = wm * 32 + mi * 16 + lg * 4 + j;
                    *(float*)(lds + row * 512 + col * 4) = acc[mi][ni][j];
                }
            }
        __syncthreads();
        float* o = (float*)outp;
        const int row = tid >> 3, ob = (tid & 7) * 64;
        const int grow = m0 + row;
        if (grow < M) {
#pragma unroll
            for (int i = 0; i < 4; i++)
                *(int4v*)((char*)o + grow * 512 + ob + i * 16) =
                    *(const int4v*)(lds + row * 512 + ob + i * 16);
        }
    }
}

// ---------------- final gather (float4) ----------------

__global__ __launch_bounds__(256) void gather_out_kernel(const float* __restrict__ hOut,
                                                         const int* __restrict__ head,
                                                         const int* __restrict__ tail,
                                                         float* __restrict__ out) {
    const int gid = blockIdx.x * 256 + threadIdx.x;
    const int q = gid >> 5, c = gid & 31;
    if (q >= 2 * NQ || c >= 25) return;
    const int node = (q < NQ) ? head[q] : tail[q - NQ];
    f32x4 v = *(const f32x4*)(hOut + (size_t)node * 128 + c * 4);
    *(f32x4*)(out + (size_t)q * OD + c * 4) = v;
}

// ---------------- launch ----------------

extern "C" void kernel_launch(void* const* d_in, const int* in_sizes, int n_in,
                              void* d_out, int out_size, void* d_ws, size_t ws_size,
                              hipStream_t stream) {
    const float* feature = (const float*)d_in[0];
    const float* Wr_h    = (const float*)d_in[1];   // [2][4][128][128]
    const float* Ws_h    = (const float*)d_in[2];   // [2][128][128]
    const float* Wr_o    = (const float*)d_in[3];   // [4][128][100]
    const float* Ws_o    = (const float*)d_in[4];   // [128][100]
    const int* edge_src  = (const int*)d_in[5];
    const int* edge_dst  = (const int*)d_in[6];
    const int* head_idx  = (const int*)d_in[7];
    const int* tail_idx  = (const int*)d_in[8];
    float* out = (float*)d_out;

    char* ws = (char*)d_ws;
    size_t off = 0;
    auto alloc = [&](size_t bytes) -> void* {
        void* p = ws + off;
        off += (bytes + 255) & ~(size_t)255;
        return p;
    };
    unsigned short* hA   = (unsigned short*)alloc((size_t)NN * HD * 2);
    unsigned short* hB   = (unsigned short*)alloc((size_t)NN * HD * 2);
    float*          hOut = (float*)alloc((size_t)NN * 128 * 4);
    unsigned short* WtH0 = (unsigned short*)alloc(128 * 640 * 2);
    unsigned short* WtH1 = (unsigned short*)alloc(128 * 640 * 2);
    unsigned short* WtO  = (unsigned short*)alloc(128 * 640 * 2);
    int*            deg  = (int*)alloc((size_t)NR * NN * 4);
    int*            rowS = (int*)alloc((size_t)NR * (NN + 1) * 4);
    int*            curs = (int*)alloc((size_t)NR * NN * 4);
    int*            csrS = (int*)alloc((size_t)NR * NE * 4 + 64);   // +pad for int4 overrun
    int*            excl = (int*)alloc((size_t)NR * NN * 4);
    int*            bsum = (int*)alloc((size_t)NR * NB_SCAN * 4);
    (void)ws_size;

    // graph prep
    zero_deg_kernel<<<(NR * NN + 255) / 256, 256, 0, stream>>>(deg);
    count_deg_kernel<<<(NR * NE + 255) / 256, 256, 0, stream>>>(edge_dst, deg);
    scanA_kernel<<<NR * NB_SCAN, 256, 0, stream>>>(deg, excl, bsum);
    scanB_kernel<<<NR, 256, 0, stream>>>(bsum);
    scanC_kernel<<<NR * NB_SCAN, 256, 0, stream>>>(excl, bsum, rowS, curs);
    fill_csr_kernel<<<(NR * NE + 255) / 256, 256, 0, stream>>>(edge_src, edge_dst, curs, csrS);

    // weight / feature prep
    conv_feat_kernel<<<(NN * HD / 4 + 255) / 256, 256, 0, stream>>>(feature, hA);
    prep_wh_kernel<<<128, 640, 0, stream>>>(Ws_h, Wr_h, WtH0);
    prep_wh_kernel<<<128, 640, 0, stream>>>(Ws_h + HD * HD, Wr_h + NR * HD * HD, WtH1);
    prep_wo_kernel<<<128, 640, 0, stream>>>(Ws_o, Wr_o, WtO);

    const int fblocks = (NN + 63) / 64;   // 782

    fused_kernel<0><<<fblocks, 512, 0, stream>>>(hA, WtH0, rowS, csrS, hB, NN);
    fused_kernel<0><<<fblocks, 512, 0, stream>>>(hB, WtH1, rowS, csrS, hA, NN);
    fused_kernel<1><<<fblocks, 512, 0, stream>>>(hA, WtO,  rowS, csrS, hOut, NN);

    gather_out_kernel<<<(2 * NQ * 32 + 255) / 256, 256, 0, stream>>>(hOut, head_idx, tail_idx, out);
}

// Round 8
// 302.315 us; speedup vs baseline: 1.2704x; 1.2704x over previous
//
#include <hip/hip_runtime.h>
#include <hip/hip_bf16.h>

#define NN 50000     // nodes
#define NR 4         // relations
#define NE 160000    // edges per relation
#define HD 128       // hidden dim
#define OD 100       // out dim
#define NQ 8192      // queries
#define NB_SCAN 196  // 196*256 >= NN

typedef __attribute__((ext_vector_type(8))) short bf16x8;
typedef __attribute__((ext_vector_type(4))) float f32x4;
typedef __attribute__((ext_vector_type(4))) int int4v;

static __device__ __forceinline__ unsigned short f2bf(float f) {
    union { float f; unsigned int u; } v; v.f = f;
    unsigned int u = v.u;
    unsigned int r = u + 0x7FFFu + ((u >> 16) & 1u);   // RNE
    return (unsigned short)(r >> 16);
}
static __device__ __forceinline__ float bflo(unsigned int v) {
    union { unsigned int u; float f; } x; x.u = v << 16; return x.f;
}
static __device__ __forceinline__ float bfhi(unsigned int v) {
    union { unsigned int u; float f; } x; x.u = v & 0xffff0000u; return x.f;
}

// ---------------- graph preprocessing ----------------

__global__ void count_deg_kernel(const int* __restrict__ edge_dst, int* __restrict__ deg) {
    int i = blockIdx.x * 256 + threadIdx.x;
    if (i < NR * NE) {
        int r = i / NE;
        atomicAdd(&deg[r * NN + edge_dst[i]], 1);
    }
}

__global__ __launch_bounds__(256) void scanA_kernel(const int* __restrict__ deg,
                                                    int* __restrict__ excl,
                                                    int* __restrict__ bsum) {
    const int r = blockIdx.x / NB_SCAN;
    const int b = blockIdx.x % NB_SCAN;
    const int tid = threadIdx.x;
    const int idx = b * 256 + tid;
    int v = (idx < NN) ? deg[r * NN + idx] : 0;
    __shared__ int buf[256];
    buf[tid] = v; __syncthreads();
    int sum = v;
    for (int off = 1; off < 256; off <<= 1) {
        int t = (tid >= off) ? buf[tid - off] : 0;
        __syncthreads();
        sum += t; buf[tid] = sum;
        __syncthreads();
    }
    if (idx < NN) excl[r * NN + idx] = sum - v;
    if (tid == 255) bsum[r * NB_SCAN + b] = sum;
}

__global__ __launch_bounds__(256) void scanB_kernel(int* __restrict__ bsum) {
    const int r = blockIdx.x;
    const int tid = threadIdx.x;
    int v = (tid < NB_SCAN) ? bsum[r * NB_SCAN + tid] : 0;
    __shared__ int buf[256];
    buf[tid] = v; __syncthreads();
    int sum = v;
    for (int off = 1; off < 256; off <<= 1) {
        int t = (tid >= off) ? buf[tid - off] : 0;
        __syncthreads();
        sum += t; buf[tid] = sum;
        __syncthreads();
    }
    if (tid < NB_SCAN) bsum[r * NB_SCAN + tid] = sum - v;
}

__global__ __launch_bounds__(256) void scanC_kernel(const int* __restrict__ excl,
                                                    const int* __restrict__ bsum,
                                                    int* __restrict__ row_start,
                                                    int* __restrict__ cursor) {
    const int r = blockIdx.x / NB_SCAN;
    const int b = blockIdx.x % NB_SCAN;
    const int idx = b * 256 + threadIdx.x;
    if (idx < NN) {
        int v = excl[r * NN + idx] + bsum[r * NB_SCAN + b];
        row_start[r * (NN + 1) + idx] = v;
        cursor[r * NN + idx] = v;
    }
    if (b == 0 && threadIdx.x == 0) row_start[r * (NN + 1) + NN] = NE;
}

__global__ void fill_csr_kernel(const int* __restrict__ edge_src,
                                const int* __restrict__ edge_dst,
                                int* __restrict__ cursor, int* __restrict__ csr_src) {
    int i = blockIdx.x * 256 + threadIdx.x;
    if (i < NR * NE) {
        int r = i / NE;
        int dst = edge_dst[i];
        int pos = atomicAdd(&cursor[r * NN + dst], 1);
        csr_src[r * NE + pos] = edge_src[i];
    }
}

// ---------------- weight / feature prep ----------------

__global__ void conv_feat_kernel(const float* __restrict__ f, unsigned short* __restrict__ h) {
    int i = (blockIdx.x * 256 + threadIdx.x) * 4;
    if (i < NN * HD) {
        h[i + 0] = f2bf(f[i + 0]);
        h[i + 1] = f2bf(f[i + 1]);
        h[i + 2] = f2bf(f[i + 2]);
        h[i + 3] = f2bf(f[i + 3]);
    }
}

// Wt [3][128 cols][640 k] bf16. layer 0/1: k<128 -> Ws_h[l][k][c], else Wr_h[l][r][kk][c].
// layer 2: cols >= 100 zero; k<128 -> Ws_o[k][c], else Wr_o[r][kk][c].
__global__ void prep_w_kernel(const float* __restrict__ Ws_h, const float* __restrict__ Wr_h,
                              const float* __restrict__ Ws_o, const float* __restrict__ Wr_o,
                              unsigned short* __restrict__ Wt) {
    const int l = blockIdx.y;     // 0..2
    const int c = blockIdx.x;     // 128
    const int k = threadIdx.x;    // 640
    float v = 0.0f;
    if (l < 2) {
        if (k < HD) v = Ws_h[(l * HD + k) * HD + c];
        else {
            int r = (k - HD) >> 7, kk = (k - HD) & 127;
            v = Wr_h[((l * NR + r) * HD + kk) * HD + c];
        }
    } else if (c < OD) {
        if (k < HD) v = Ws_o[k * OD + c];
        else {
            int r = (k - HD) >> 7, kk = (k - HD) & 127;
            v = Wr_o[(r * HD + kk) * OD + c];
        }
    }
    Wt[(l * 128 + c) * 640 + k] = f2bf(v);
}

// ---------------- fused: reg-accumulated gather + GEMM ----------------
// Block = 512 thr (8 waves), 32 nodes. LDS 40KB: [0,8192) hT ; [8192,40960) agg.
// Phase 0: stage h tile [32][256B] -> LDS (swizzled), 1 x 16B per thread.
// Phase 1: wave w handles nodes 4w..4w+3 sequentially; lane-group g (16 lanes
//          x 16B = full 256B h row) = relation g. Per node: 4 srcs + 4 h-rows
//          issued in parallel (depth-4 pipeline), 2 edges consumed per
//          iteration; fp32 reg accumulate; scale by 1/(e-s) (CSR run length
//          IS the degree); one swizzled ds_write_b128. No atomics.
// Phase 2: GEMM [hT | agg](32x640) @ Wt(128x640)^T. Wave w owns 16 cols;
//          A from LDS (XOR swizzle), B direct from global Wt (L2-resident);
//          20 K-steps, no barriers in loop.
// MODE 0: relu + bf16 out via LDS bounce. MODE 1: f32 out via LDS bounce.

template<int MODE>
__global__ __launch_bounds__(512, 2)
void fused_kernel(const unsigned short* __restrict__ h,
                  const unsigned short* __restrict__ Bt,
                  const int* __restrict__ row_start,
                  const int* __restrict__ csr_src,
                  void* __restrict__ outp, int M) {
    __shared__ __align__(16) char lds[40960];   // [0,8192) hT ; [8192,40960) agg
    const int tid = threadIdx.x;
    const int m0 = blockIdx.x * 32;
    const int lane = tid & 63;
    const int w = tid >> 6;            // 0..7

    // ---- phase 0: stage h tile ----
    {
        const int row = tid >> 4, kb = (tid & 15) * 16;
        int gr = m0 + row; if (gr >= M) gr = M - 1;
        int4v v = *(const int4v*)((const char*)h + (size_t)gr * 256 + kb);
        *(int4v*)(lds + row * 256 + (kb ^ ((row & 7) << 4))) = v;
    }

    // ---- phase 1: gather (4 relations in parallel via lane groups) ----
    {
        const int g = lane >> 4, li = lane & 15;
        const int* __restrict__ csr = csr_src + (size_t)g * NE;
        const char* hp = (const char*)h + li * 16;

#pragma unroll
        for (int i = 0; i < 4; ++i) {
            const int n = m0 + (w << 2) + i;
            const bool vn = n < M;
            const int s = vn ? row_start[g * (NN + 1) + n] : 0;
            const int e = vn ? row_start[g * (NN + 1) + n + 1] : 0;

            f32x4 A = {0.f, 0.f, 0.f, 0.f}, B = {0.f, 0.f, 0.f, 0.f};
            int t = s;
            int s4 = 0, s5 = 0;
            int4v v0 = {0,0,0,0}, v1 = v0, v2 = v0, v3 = v0;
            {
                int a0 = 0, a1 = 0, a2 = 0, a3 = 0;
                if (t     < e) a0 = csr[t];
                if (t + 1 < e) a1 = csr[t + 1];
                if (t + 2 < e) a2 = csr[t + 2];
                if (t + 3 < e) a3 = csr[t + 3];
                if (t + 4 < e) s4 = csr[t + 4];
                if (t + 5 < e) s5 = csr[t + 5];
                if (t     < e) v0 = *(const int4v*)(hp + (size_t)a0 * 256);
                if (t + 1 < e) v1 = *(const int4v*)(hp + (size_t)a1 * 256);
                if (t + 2 < e) v2 = *(const int4v*)(hp + (size_t)a2 * 256);
                if (t + 3 < e) v3 = *(const int4v*)(hp + (size_t)a3 * 256);
            }
            while (__any(t < e)) {
                if (t < e) {
                    const unsigned int* vu = (const unsigned int*)&v0;
                    A[0] += bflo(vu[0]); A[1] += bfhi(vu[0]);
                    A[2] += bflo(vu[1]); A[3] += bfhi(vu[1]);
                    B[0] += bflo(vu[2]); B[1] += bfhi(vu[2]);
                    B[2] += bflo(vu[3]); B[3] += bfhi(vu[3]);
                }
                if (t + 1 < e) {
                    const unsigned int* vu = (const unsigned int*)&v1;
                    A[0] += bflo(vu[0]); A[1] += bfhi(vu[0]);
                    A[2] += bflo(vu[1]); A[3] += bfhi(vu[1]);
                    B[0] += bflo(vu[2]); B[1] += bfhi(vu[2]);
                    B[2] += bflo(vu[3]); B[3] += bfhi(vu[3]);
                }
                v0 = v2; v1 = v3;
                if (t + 4 < e) v2 = *(const int4v*)(hp + (size_t)s4 * 256);
                if (t + 5 < e) v3 = *(const int4v*)(hp + (size_t)s5 * 256);
                if (t + 6 < e) s4 = csr[t + 6];
                if (t + 7 < e) s5 = csr[t + 7];
                t += 2;
            }
            const float inv = 1.0f / fmaxf((float)(e - s), 1.0f);
            unsigned int p0 = (unsigned int)f2bf(inv * A[0]) | ((unsigned int)f2bf(inv * A[1]) << 16);
            unsigned int p1 = (unsigned int)f2bf(inv * A[2]) | ((unsigned int)f2bf(inv * A[3]) << 16);
            unsigned int p2 = (unsigned int)f2bf(inv * B[0]) | ((unsigned int)f2bf(inv * B[1]) << 16);
            unsigned int p3 = (unsigned int)f2bf(inv * B[2]) | ((unsigned int)f2bf(inv * B[3]) << 16);
            const int row = (w << 2) + i;
            const int cb = g * 256 + li * 16;
            *(int4v*)(lds + 8192 + row * 1024 + (cb ^ ((row & 7) << 4))) =
                (int4v){(int)p0, (int)p1, (int)p2, (int)p3};
        }
    }
    __syncthreads();

    // ---- phase 2: GEMM; wave w owns output cols w*16..w*16+16 ----
    const int lr = lane & 15;
    const int lg = lane >> 4;
    const char* bB = (const char*)Bt + (size_t)(w * 16 + lr) * 1280;

    f32x4 acc[2];
    acc[0] = (f32x4){0.f, 0.f, 0.f, 0.f};
    acc[1] = (f32x4){0.f, 0.f, 0.f, 0.f};

#pragma unroll
    for (int kb = 0; kb < 20; ++kb) {
        const int kByte = kb * 64 + lg * 16;
        bf16x8 bfr = *(const bf16x8*)(bB + kByte);
#pragma unroll
        for (int mi = 0; mi < 2; mi++) {
            const int row = mi * 16 + lr;
            int off;
            if (kb < 4) off = row * 256 + (kByte ^ ((row & 7) << 4));
            else        off = 8192 + row * 1024 + ((kByte - 256) ^ ((row & 7) << 4));
            bf16x8 af = *(const bf16x8*)(lds + off);
            acc[mi] = __builtin_amdgcn_mfma_f32_16x16x32_bf16(af, bfr, acc[mi], 0, 0, 0);
        }
    }

    __syncthreads();                        // all A-reads done; reuse LDS as bounce

    if (MODE == 0) {
        // relu -> bf16 tile [32][256B] at lds[0..8192)
#pragma unroll
        for (int mi = 0; mi < 2; mi++) {
            const int col = w * 16 + lr;
#pragma unroll
            for (int j = 0; j < 4; j++) {
                const int row = mi * 16 + lg * 4 + j;
                *(unsigned short*)(lds + row * 256 + col * 2) =
                    f2bf(fmaxf(acc[mi][j], 0.f));
            }
        }
        __syncthreads();
        unsigned short* o = (unsigned short*)outp;
        const int row = tid >> 4, kb = (tid & 15) * 16;
        const int grow = m0 + row;
        if (grow < M)
            *(int4v*)((char*)o + (size_t)grow * 256 + kb) = *(const int4v*)(lds + row * 256 + kb);
    } else {
        // f32 tile [32][512B] at lds[0..16384)
#pragma unroll
        for (int mi = 0; mi < 2; mi++) {
            const int col = w * 16 + lr;
#pragma unroll
            for (int j = 0; j < 4; j++) {
                const int row = mi * 16 + lg * 4 + j;
                *(float*)(lds + row * 512 + col * 4) = acc[mi][j];
            }
        }
        __syncthreads();
        float* o = (float*)outp;
#pragma unroll
        for (int i = 0; i < 2; i++) {
            const int c = tid + i * 512;       // 1024 chunks of 16B
            const int row = c >> 5, o16 = (c & 31) * 16;
            const int grow = m0 + row;
            if (grow < M)
                *(int4v*)((char*)o + (size_t)grow * 512 + o16) = *(const int4v*)(lds + row * 512 + o16);
        }
    }
}

// ---------------- final gather (float4) ----------------

__global__ __launch_bounds__(256) void gather_out_kernel(const float* __restrict__ hOut,
                                                         const int* __restrict__ head,
                                                         const int* __restrict__ tail,
                                                         float* __restrict__ out) {
    const int gid = blockIdx.x * 256 + threadIdx.x;
    const int q = gid >> 5, c = gid & 31;
    if (q >= 2 * NQ || c >= 25) return;
    const int node = (q < NQ) ? head[q] : tail[q - NQ];
    f32x4 v = *(const f32x4*)(hOut + (size_t)node * 128 + c * 4);
    *(f32x4*)(out + (size_t)q * OD + c * 4) = v;
}

// ---------------- launch ----------------

extern "C" void kernel_launch(void* const* d_in, const int* in_sizes, int n_in,
                              void* d_out, int out_size, void* d_ws, size_t ws_size,
                              hipStream_t stream) {
    const float* feature = (const float*)d_in[0];
    const float* Wr_h    = (const float*)d_in[1];   // [2][4][128][128]
    const float* Ws_h    = (const float*)d_in[2];   // [2][128][128]
    const float* Wr_o    = (const float*)d_in[3];   // [4][128][100]
    const float* Ws_o    = (const float*)d_in[4];   // [128][100]
    const int* edge_src  = (const int*)d_in[5];
    const int* edge_dst  = (const int*)d_in[6];
    const int* head_idx  = (const int*)d_in[7];
    const int* tail_idx  = (const int*)d_in[8];
    float* out = (float*)d_out;

    char* ws = (char*)d_ws;
    size_t off = 0;
    auto alloc = [&](size_t bytes) -> void* {
        void* p = ws + off;
        off += (bytes + 255) & ~(size_t)255;
        return p;
    };
    unsigned short* hA   = (unsigned short*)alloc((size_t)NN * HD * 2);
    unsigned short* hB   = (unsigned short*)alloc((size_t)NN * HD * 2);
    float*          hOut = (float*)alloc((size_t)NN * 128 * 4);
    unsigned short* Wt   = (unsigned short*)alloc((size_t)3 * 128 * 640 * 2);
    int*            deg  = (int*)alloc((size_t)NR * NN * 4);
    int*            rowS = (int*)alloc((size_t)NR * (NN + 1) * 4);
    int*            curs = (int*)alloc((size_t)NR * NN * 4);
    int*            csrS = (int*)alloc((size_t)NR * NE * 4 + 64);
    int*            excl = (int*)alloc((size_t)NR * NN * 4);
    int*            bsum = (int*)alloc((size_t)NR * NB_SCAN * 4);
    (void)ws_size;

    // graph prep
    hipMemsetAsync(deg, 0, (size_t)NR * NN * 4, stream);
    count_deg_kernel<<<(NR * NE + 255) / 256, 256, 0, stream>>>(edge_dst, deg);
    scanA_kernel<<<NR * NB_SCAN, 256, 0, stream>>>(deg, excl, bsum);
    scanB_kernel<<<NR, 256, 0, stream>>>(bsum);
    scanC_kernel<<<NR * NB_SCAN, 256, 0, stream>>>(excl, bsum, rowS, curs);
    fill_csr_kernel<<<(NR * NE + 255) / 256, 256, 0, stream>>>(edge_src, edge_dst, curs, csrS);

    // weight / feature prep
    conv_feat_kernel<<<(NN * HD / 4 + 255) / 256, 256, 0, stream>>>(feature, hA);
    prep_w_kernel<<<dim3(128, 3), 640, 0, stream>>>(Ws_h, Wr_h, Ws_o, Wr_o, Wt);

    const int fblocks = (NN + 31) / 32;   // 1563
    unsigned short* WtH0 = Wt;
    unsigned short* WtH1 = Wt + 128 * 640;
    unsigned short* WtO  = Wt + 2 * 128 * 640;

    fused_kernel<0><<<fblocks, 512, 0, stream>>>(hA, WtH0, rowS, csrS, hB, NN);
    fused_kernel<0><<<fblocks, 512, 0, stream>>>(hB, WtH1, rowS, csrS, hA, NN);
    fused_kernel<1><<<fblocks, 512, 0, stream>>>(hA, WtO,  rowS, csrS, hOut, NN);

    gather_out_kernel<<<(2 * NQ * 32 + 255) / 256, 256, 0, stream>>>(hOut, head_idx, tail_idx, out);
}

// Round 9
// 273.086 us; speedup vs baseline: 1.4063x; 1.1070x over previous
//
#include <hip/hip_runtime.h>
#include <hip/hip_bf16.h>

#define NN 50000     // nodes
#define NR 4         // relations
#define NE 160000    // edges per relation
#define HD 128       // hidden dim
#define OD 100       // out dim
#define NQ 8192      // queries
#define NB_SCAN 196  // 196*256 >= NN

// merged-prep region sizes (all exact multiples of 256)
#define NB_COUNT 2500   // NR*NE/256
#define NB_CONV  6250   // NN*HD/4/256
#define NB_PREPW 960    // 3*128*640/256

typedef __attribute__((ext_vector_type(8))) short bf16x8;
typedef __attribute__((ext_vector_type(4))) float f32x4;
typedef __attribute__((ext_vector_type(4))) int int4v;

static __device__ __forceinline__ unsigned short f2bf(float f) {
    union { float f; unsigned int u; } v; v.f = f;
    unsigned int u = v.u;
    unsigned int r = u + 0x7FFFu + ((u >> 16) & 1u);   // RNE
    return (unsigned short)(r >> 16);
}
static __device__ __forceinline__ float bflo(unsigned int v) {
    union { unsigned int u; float f; } x; x.u = v << 16; return x.f;
}
static __device__ __forceinline__ float bfhi(unsigned int v) {
    union { unsigned int u; float f; } x; x.u = v & 0xffff0000u; return x.f;
}

// ---------------- merged prep: count_deg | conv_feat | prep_w ----------------

__global__ __launch_bounds__(256) void prep_merged_kernel(
        const int* __restrict__ edge_dst, int* __restrict__ deg,
        const float* __restrict__ feature, unsigned short* __restrict__ h,
        const float* __restrict__ Ws_h, const float* __restrict__ Wr_h,
        const float* __restrict__ Ws_o, const float* __restrict__ Wr_o,
        unsigned short* __restrict__ Wt) {
    const int b = blockIdx.x;
    if (b < NB_COUNT) {
        const int i = b * 256 + threadIdx.x;            // < NR*NE exactly
        const int r = i / NE;
        atomicAdd(&deg[r * NN + edge_dst[i]], 1);
    } else if (b < NB_COUNT + NB_CONV) {
        const int i = ((b - NB_COUNT) * 256 + threadIdx.x) * 4;  // < NN*HD exactly
        h[i + 0] = f2bf(feature[i + 0]);
        h[i + 1] = f2bf(feature[i + 1]);
        h[i + 2] = f2bf(feature[i + 2]);
        h[i + 3] = f2bf(feature[i + 3]);
    } else {
        const int idx = (b - NB_COUNT - NB_CONV) * 256 + threadIdx.x;  // < 3*128*640
        const int l = idx / (128 * 640);
        const int rem = idx % (128 * 640);
        const int c = rem / 640;
        const int k = rem % 640;
        float v = 0.0f;
        if (l < 2) {
            if (k < HD) v = Ws_h[(l * HD + k) * HD + c];
            else {
                int r = (k - HD) >> 7, kk = (k - HD) & 127;
                v = Wr_h[((l * NR + r) * HD + kk) * HD + c];
            }
        } else if (c < OD) {
            if (k < HD) v = Ws_o[k * OD + c];
            else {
                int r = (k - HD) >> 7, kk = (k - HD) & 127;
                v = Wr_o[(r * HD + kk) * OD + c];
            }
        }
        Wt[idx] = f2bf(v);
    }
}

// ---------------- scan ----------------

__global__ __launch_bounds__(256) void scanA_kernel(const int* __restrict__ deg,
                                                    int* __restrict__ excl,
                                                    int* __restrict__ bsum) {
    const int r = blockIdx.x / NB_SCAN;
    const int b = blockIdx.x % NB_SCAN;
    const int tid = threadIdx.x;
    const int idx = b * 256 + tid;
    int v = (idx < NN) ? deg[r * NN + idx] : 0;
    __shared__ int buf[256];
    buf[tid] = v; __syncthreads();
    int sum = v;
    for (int off = 1; off < 256; off <<= 1) {
        int t = (tid >= off) ? buf[tid - off] : 0;
        __syncthreads();
        sum += t; buf[tid] = sum;
        __syncthreads();
    }
    if (idx < NN) excl[r * NN + idx] = sum - v;
    if (tid == 255) bsum[r * NB_SCAN + b] = sum;
}

// scanC with inlined chunk-prefix reduction (replaces scanB)
__global__ __launch_bounds__(256) void scanC_kernel(const int* __restrict__ excl,
                                                    const int* __restrict__ bsum,
                                                    int* __restrict__ row_start,
                                                    int* __restrict__ cursor) {
    const int r = blockIdx.x / NB_SCAN;
    const int b = blockIdx.x % NB_SCAN;
    const int tid = threadIdx.x;
    __shared__ int buf[256];
    // prefix = sum of bsum[r][0..b-1]  (b <= 195 < 256)
    buf[tid] = (tid < b) ? bsum[r * NB_SCAN + tid] : 0;
    __syncthreads();
    for (int off = 128; off > 0; off >>= 1) {
        if (tid < off) buf[tid] += buf[tid + off];
        __syncthreads();
    }
    const int prefix = buf[0];
    const int idx = b * 256 + tid;
    if (idx < NN) {
        int v = excl[r * NN + idx] + prefix;
        row_start[r * (NN + 1) + idx] = v;
        cursor[r * NN + idx] = v;
    }
    if (b == 0 && tid == 0) row_start[r * (NN + 1) + NN] = NE;
}

__global__ __launch_bounds__(256) void fill_csr_kernel(const int* __restrict__ edge_src,
                                                       const int* __restrict__ edge_dst,
                                                       int* __restrict__ cursor,
                                                       int* __restrict__ csr_src) {
    const int i = blockIdx.x * 256 + threadIdx.x;     // < NR*NE exactly
    const int r = i / NE;
    const int dst = edge_dst[i];
    const int pos = atomicAdd(&cursor[r * NN + dst], 1);
    csr_src[r * NE + pos] = edge_src[i];
}

// ---------------- fused: reg-accumulated gather + GEMM (round-6 form) ----------------
// Block = 512 thr (8 waves), 32 nodes. LDS 40KB: [0,8192) hT ; [8192,40960) agg.
// Phase 0: stage h tile [32][256B] -> LDS (swizzled), 1 x 16B per thread.
// Phase 1: wave w handles nodes 4w..4w+3 sequentially; lane-group g (16 lanes
//          x 16B = full 256B h row) = relation g. Srcs prefetched 3-deep,
//          values 2-deep; fp32 reg accumulate; scale by 1/(e-s) (CSR run
//          length IS the degree); one swizzled ds_write_b128. No atomics.
// Phase 2: GEMM [hT | agg](32x640) @ Wt(128x640)^T. Wave w owns 16 cols;
//          A from LDS (XOR swizzle), B direct from global Wt (L2-resident);
//          20 K-steps, no barriers in loop.
// MODE 0: relu + bf16 out via LDS bounce. MODE 1: f32 out via LDS bounce.

template<int MODE>
__global__ __launch_bounds__(512, 2)
void fused_kernel(const unsigned short* __restrict__ h,
                  const unsigned short* __restrict__ Bt,
                  const int* __restrict__ row_start,
                  const int* __restrict__ csr_src,
                  void* __restrict__ outp, int M) {
    __shared__ __align__(16) char lds[40960];   // [0,8192) hT ; [8192,40960) agg
    const int tid = threadIdx.x;
    const int m0 = blockIdx.x * 32;
    const int lane = tid & 63;
    const int w = tid >> 6;            // 0..7

    // ---- phase 0: stage h tile ----
    {
        const int row = tid >> 4, kb = (tid & 15) * 16;
        int gr = m0 + row; if (gr >= M) gr = M - 1;
        int4v v = *(const int4v*)((const char*)h + (size_t)gr * 256 + kb);
        *(int4v*)(lds + row * 256 + (kb ^ ((row & 7) << 4))) = v;
    }

    // ---- phase 1: gather (4 relations in parallel via lane groups) ----
    {
        const int g = lane >> 4, li = lane & 15;
        const int* __restrict__ csr = csr_src + (size_t)g * NE;
        const char* hp = (const char*)h + li * 16;

#pragma unroll
        for (int i = 0; i < 4; ++i) {
            const int n = m0 + (w << 2) + i;
            const bool vn = n < M;
            const int s = vn ? row_start[g * (NN + 1) + n] : 0;
            const int e = vn ? row_start[g * (NN + 1) + n + 1] : 0;

            f32x4 a0 = {0.f, 0.f, 0.f, 0.f}, a1 = {0.f, 0.f, 0.f, 0.f};
            int t = s;
            int sC = 0;
            int4v v0 = {0,0,0,0}, v1 = {0,0,0,0};
            {
                int sA = 0, sB = 0;
                if (t     < e) sA = csr[t];
                if (t + 1 < e) sB = csr[t + 1];
                if (t + 2 < e) sC = csr[t + 2];
                if (t     < e) v0 = *(const int4v*)(hp + (size_t)sA * 256);
                if (t + 1 < e) v1 = *(const int4v*)(hp + (size_t)sB * 256);
            }
            while (__any(t < e)) {
                const bool act = t < e;
                const int4v vc = v0;
                v0 = v1;
                if (t + 2 < e) v1 = *(const int4v*)(hp + (size_t)sC * 256);
                sC = (t + 3 < e) ? csr[t + 3] : 0;
                if (act) {
                    const unsigned int* vu = (const unsigned int*)&vc;
                    a0[0] += bflo(vu[0]); a0[1] += bfhi(vu[0]);
                    a0[2] += bflo(vu[1]); a0[3] += bfhi(vu[1]);
                    a1[0] += bflo(vu[2]); a1[1] += bfhi(vu[2]);
                    a1[2] += bflo(vu[3]); a1[3] += bfhi(vu[3]);
                }
                ++t;
            }
            const float wd = 1.0f / fmaxf((float)(e - s), 1.0f);
            unsigned int p0 = (unsigned int)f2bf(wd * a0[0]) | ((unsigned int)f2bf(wd * a0[1]) << 16);
            unsigned int p1 = (unsigned int)f2bf(wd * a0[2]) | ((unsigned int)f2bf(wd * a0[3]) << 16);
            unsigned int p2 = (unsigned int)f2bf(wd * a1[0]) | ((unsigned int)f2bf(wd * a1[1]) << 16);
            unsigned int p3 = (unsigned int)f2bf(wd * a1[2]) | ((unsigned int)f2bf(wd * a1[3]) << 16);
            const int row = (w << 2) + i;
            const int cb = g * 256 + li * 16;
            *(int4v*)(lds + 8192 + row * 1024 + (cb ^ ((row & 7) << 4))) =
                (int4v){(int)p0, (int)p1, (int)p2, (int)p3};
        }
    }
    __syncthreads();

    // ---- phase 2: GEMM; wave w owns output cols w*16..w*16+16 ----
    const int lr = lane & 15;
    const int lg = lane >> 4;
    const char* bB = (const char*)Bt + (size_t)(w * 16 + lr) * 1280;

    f32x4 acc[2];
    acc[0] = (f32x4){0.f, 0.f, 0.f, 0.f};
    acc[1] = (f32x4){0.f, 0.f, 0.f, 0.f};

#pragma unroll
    for (int kb = 0; kb < 20; ++kb) {
        const int kByte = kb * 64 + lg * 16;
        bf16x8 bfr = *(const bf16x8*)(bB + kByte);
#pragma unroll
        for (int mi = 0; mi < 2; mi++) {
            const int row = mi * 16 + lr;
            int off;
            if (kb < 4) off = row * 256 + (kByte ^ ((row & 7) << 4));
            else        off = 8192 + row * 1024 + ((kByte - 256) ^ ((row & 7) << 4));
            bf16x8 af = *(const bf16x8*)(lds + off);
            acc[mi] = __builtin_amdgcn_mfma_f32_16x16x32_bf16(af, bfr, acc[mi], 0, 0, 0);
        }
    }

    __syncthreads();                        // all A-reads done; reuse LDS as bounce

    if (MODE == 0) {
        // relu -> bf16 tile [32][256B] at lds[0..8192)
#pragma unroll
        for (int mi = 0; mi < 2; mi++) {
            const int col = w * 16 + lr;
#pragma unroll
            for (int j = 0; j < 4; j++) {
                const int row = mi * 16 + lg * 4 + j;
                *(unsigned short*)(lds + row * 256 + col * 2) =
                    f2bf(fmaxf(acc[mi][j], 0.f));
            }
        }
        __syncthreads();
        unsigned short* o = (unsigned short*)outp;
        const int row = tid >> 4, kb = (tid & 15) * 16;
        const int grow = m0 + row;
        if (grow < M)
            *(int4v*)((char*)o + (size_t)grow * 256 + kb) = *(const int4v*)(lds + row * 256 + kb);
    } else {
        // f32 tile [32][512B] at lds[0..16384)
#pragma unroll
        for (int mi = 0; mi < 2; mi++) {
            const int col = w * 16 + lr;
#pragma unroll
            for (int j = 0; j < 4; j++) {
                const int row = mi * 16 + lg * 4 + j;
                *(float*)(lds + row * 512 + col * 4) = acc[mi][j];
            }
        }
        __syncthreads();
        float* o = (float*)outp;
#pragma unroll
        for (int i = 0; i < 2; i++) {
            const int c = tid + i * 512;       // 1024 chunks of 16B
            const int row = c >> 5, o16 = (c & 31) * 16;
            const int grow = m0 + row;
            if (grow < M)
                *(int4v*)((char*)o + (size_t)grow * 512 + o16) = *(const int4v*)(lds + row * 512 + o16);
        }
    }
}

// ---------------- final gather (float4) ----------------

__global__ __launch_bounds__(256) void gather_out_kernel(const float* __restrict__ hOut,
                                                         const int* __restrict__ head,
                                                         const int* __restrict__ tail,
                                                         float* __restrict__ out) {
    const int gid = blockIdx.x * 256 + threadIdx.x;
    const int q = gid >> 5, c = gid & 31;
    if (q >= 2 * NQ || c >= 25) return;
    const int node = (q < NQ) ? head[q] : tail[q - NQ];
    f32x4 v = *(const f32x4*)(hOut + (size_t)node * 128 + c * 4);
    *(f32x4*)(out + (size_t)q * OD + c * 4) = v;
}

// ---------------- launch ----------------

extern "C" void kernel_launch(void* const* d_in, const int* in_sizes, int n_in,
                              void* d_out, int out_size, void* d_ws, size_t ws_size,
                              hipStream_t stream) {
    const float* feature = (const float*)d_in[0];
    const float* Wr_h    = (const float*)d_in[1];   // [2][4][128][128]
    const float* Ws_h    = (const float*)d_in[2];   // [2][128][128]
    const float* Wr_o    = (const float*)d_in[3];   // [4][128][100]
    const float* Ws_o    = (const float*)d_in[4];   // [128][100]
    const int* edge_src  = (const int*)d_in[5];
    const int* edge_dst  = (const int*)d_in[6];
    const int* head_idx  = (const int*)d_in[7];
    const int* tail_idx  = (const int*)d_in[8];
    float* out = (float*)d_out;

    char* ws = (char*)d_ws;
    size_t off = 0;
    auto alloc = [&](size_t bytes) -> void* {
        void* p = ws + off;
        off += (bytes + 255) & ~(size_t)255;
        return p;
    };
    unsigned short* hA   = (unsigned short*)alloc((size_t)NN * HD * 2);
    unsigned short* hB   = (unsigned short*)alloc((size_t)NN * HD * 2);
    float*          hOut = (float*)alloc((size_t)NN * 128 * 4);
    unsigned short* Wt   = (unsigned short*)alloc((size_t)3 * 128 * 640 * 2);
    int*            deg  = (int*)alloc((size_t)NR * NN * 4);
    int*            rowS = (int*)alloc((size_t)NR * (NN + 1) * 4);
    int*            curs = (int*)alloc((size_t)NR * NN * 4);
    int*            csrS = (int*)alloc((size_t)NR * NE * 4 + 64);
    int*            excl = (int*)alloc((size_t)NR * NN * 4);
    int*            bsum = (int*)alloc((size_t)NR * NB_SCAN * 4);
    (void)ws_size;

    // prep: zero deg, then merged {count_deg | conv_feat | prep_w}
    hipMemsetAsync(deg, 0, (size_t)NR * NN * 4, stream);
    prep_merged_kernel<<<NB_COUNT + NB_CONV + NB_PREPW, 256, 0, stream>>>(
        edge_dst, deg, feature, hA, Ws_h, Wr_h, Ws_o, Wr_o, Wt);
    scanA_kernel<<<NR * NB_SCAN, 256, 0, stream>>>(deg, excl, bsum);
    scanC_kernel<<<NR * NB_SCAN, 256, 0, stream>>>(excl, bsum, rowS, curs);
    fill_csr_kernel<<<NB_COUNT, 256, 0, stream>>>(edge_src, edge_dst, curs, csrS);

    const int fblocks = (NN + 31) / 32;   // 1563
    unsigned short* WtH0 = Wt;
    unsigned short* WtH1 = Wt + 128 * 640;
    unsigned short* WtO  = Wt + 2 * 128 * 640;

    fused_kernel<0><<<fblocks, 512, 0, stream>>>(hA, WtH0, rowS, csrS, hB, NN);
    fused_kernel<0><<<fblocks, 512, 0, stream>>>(hB, WtH1, rowS, csrS, hA, NN);
    fused_kernel<1><<<fblocks, 512, 0, stream>>>(hA, WtO,  rowS, csrS, hOut, NN);

    gather_out_kernel<<<(2 * NQ * 32 + 255) / 256, 256, 0, stream>>>(hOut, head_idx, tail_idx, out);
}

// Round 10
// 268.519 us; speedup vs baseline: 1.4303x; 1.0170x over previous
//
#include <hip/hip_runtime.h>
#include <hip/hip_bf16.h>

#define NN 50000     // nodes
#define NR 4         // relations
#define NE 160000    // edges per relation
#define HD 128       // hidden dim
#define OD 100       // out dim
#define NQ 8192      // queries
#define NB_SCAN 196  // 196*256 >= NN

// merged-prep region sizes (all exact multiples of 256)
#define NB_COUNT 2500   // NR*NE/256
#define NB_CONV  6250   // NN*HD/4/256
#define NB_PREPW 960    // 3*128*640/256

typedef __attribute__((ext_vector_type(8))) short bf16x8;
typedef __attribute__((ext_vector_type(4))) float f32x4;
typedef __attribute__((ext_vector_type(4))) int int4v;

static __device__ __forceinline__ unsigned short f2bf(float f) {
    union { float f; unsigned int u; } v; v.f = f;
    unsigned int u = v.u;
    unsigned int r = u + 0x7FFFu + ((u >> 16) & 1u);   // RNE
    return (unsigned short)(r >> 16);
}
static __device__ __forceinline__ float bflo(unsigned int v) {
    union { unsigned int u; float f; } x; x.u = v << 16; return x.f;
}
static __device__ __forceinline__ float bfhi(unsigned int v) {
    union { unsigned int u; float f; } x; x.u = v & 0xffff0000u; return x.f;
}

// ---------------- merged prep: count_deg | conv_feat | prep_w ----------------

__global__ __launch_bounds__(256) void prep_merged_kernel(
        const int* __restrict__ edge_dst, int* __restrict__ deg,
        const float* __restrict__ feature, unsigned short* __restrict__ h,
        const float* __restrict__ Ws_h, const float* __restrict__ Wr_h,
        const float* __restrict__ Ws_o, const float* __restrict__ Wr_o,
        unsigned short* __restrict__ Wt) {
    const int b = blockIdx.x;
    if (b < NB_COUNT) {
        const int i = b * 256 + threadIdx.x;            // < NR*NE exactly
        const int r = i / NE;
        atomicAdd(&deg[r * NN + edge_dst[i]], 1);
    } else if (b < NB_COUNT + NB_CONV) {
        const int i = ((b - NB_COUNT) * 256 + threadIdx.x) * 4;  // < NN*HD exactly
        h[i + 0] = f2bf(feature[i + 0]);
        h[i + 1] = f2bf(feature[i + 1]);
        h[i + 2] = f2bf(feature[i + 2]);
        h[i + 3] = f2bf(feature[i + 3]);
    } else {
        const int idx = (b - NB_COUNT - NB_CONV) * 256 + threadIdx.x;  // < 3*128*640
        const int l = idx / (128 * 640);
        const int rem = idx % (128 * 640);
        const int c = rem / 640;
        const int k = rem % 640;
        float v = 0.0f;
        if (l < 2) {
            if (k < HD) v = Ws_h[(l * HD + k) * HD + c];
            else {
                int r = (k - HD) >> 7, kk = (k - HD) & 127;
                v = Wr_h[((l * NR + r) * HD + kk) * HD + c];
            }
        } else if (c < OD) {
            if (k < HD) v = Ws_o[k * OD + c];
            else {
                int r = (k - HD) >> 7, kk = (k - HD) & 127;
                v = Wr_o[(r * HD + kk) * OD + c];
            }
        }
        Wt[idx] = f2bf(v);
    }
}

// ---------------- scan ----------------

__global__ __launch_bounds__(256) void scanA_kernel(const int* __restrict__ deg,
                                                    int* __restrict__ excl,
                                                    int* __restrict__ bsum) {
    const int r = blockIdx.x / NB_SCAN;
    const int b = blockIdx.x % NB_SCAN;
    const int tid = threadIdx.x;
    const int idx = b * 256 + tid;
    int v = (idx < NN) ? deg[r * NN + idx] : 0;
    __shared__ int buf[256];
    buf[tid] = v; __syncthreads();
    int sum = v;
    for (int off = 1; off < 256; off <<= 1) {
        int t = (tid >= off) ? buf[tid - off] : 0;
        __syncthreads();
        sum += t; buf[tid] = sum;
        __syncthreads();
    }
    if (idx < NN) excl[r * NN + idx] = sum - v;
    if (tid == 255) bsum[r * NB_SCAN + b] = sum;
}

// scanC with inlined chunk-prefix reduction (replaces scanB)
__global__ __launch_bounds__(256) void scanC_kernel(const int* __restrict__ excl,
                                                    const int* __restrict__ bsum,
                                                    int* __restrict__ row_start,
                                                    int* __restrict__ cursor) {
    const int r = blockIdx.x / NB_SCAN;
    const int b = blockIdx.x % NB_SCAN;
    const int tid = threadIdx.x;
    __shared__ int buf[256];
    // prefix = sum of bsum[r][0..b-1]  (b <= 195 < 256)
    buf[tid] = (tid < b) ? bsum[r * NB_SCAN + tid] : 0;
    __syncthreads();
    for (int off = 128; off > 0; off >>= 1) {
        if (tid < off) buf[tid] += buf[tid + off];
        __syncthreads();
    }
    const int prefix = buf[0];
    const int idx = b * 256 + tid;
    if (idx < NN) {
        int v = excl[r * NN + idx] + prefix;
        row_start[r * (NN + 1) + idx] = v;
        cursor[r * NN + idx] = v;
    }
    if (b == 0 && tid == 0) row_start[r * (NN + 1) + NN] = NE;
}

__global__ __launch_bounds__(256) void fill_csr_kernel(const int* __restrict__ edge_src,
                                                       const int* __restrict__ edge_dst,
                                                       int* __restrict__ cursor,
                                                       int* __restrict__ csr_src) {
    const int i = blockIdx.x * 256 + threadIdx.x;     // < NR*NE exactly
    const int r = i / NE;
    const int dst = edge_dst[i];
    const int pos = atomicAdd(&cursor[r * NN + dst], 1);
    csr_src[r * NE + pos] = edge_src[i];
}

// ---------------- fused: concatenated reg-gather + GEMM ----------------
// Block = 512 thr (8 waves), 32 nodes. LDS 40KB: [0,8192) hT ; [8192,40960) agg.
// Phase 0: stage h tile [32][256B] -> LDS (swizzled), 1 x 16B per thread.
// Phase 1: wave w, lane-group g (16 lanes x 16B = full 256B h row) walks the
//          CONTIGUOUS CSR range of relation g over the wave's 4 consecutive
//          nodes [m0+4w, m0+4w+4): ONE pipeline prologue per wave (srcs 3-deep,
//          values 2-deep), node boundaries in 4 shift registers, emit-on-
//          boundary = scale by 1/(e-s) + pack bf16 + one swizzled
//          ds_write_b128. fp32 reg accumulate. No atomics.
// Phase 2: GEMM [hT | agg](32x640) @ Wt(128x640)^T. Wave w owns 16 cols;
//          A from LDS (XOR swizzle), B direct from global Wt (L2-resident);
//          20 K-steps, no barriers in loop.
// MODE 0: relu + bf16 out via LDS bounce. MODE 1: f32 out via LDS bounce.

template<int MODE>
__global__ __launch_bounds__(512, 8)
void fused_kernel(const unsigned short* __restrict__ h,
                  const unsigned short* __restrict__ Bt,
                  const int* __restrict__ row_start,
                  const int* __restrict__ csr_src,
                  void* __restrict__ outp, int M) {
    __shared__ __align__(16) char lds[40960];   // [0,8192) hT ; [8192,40960) agg
    const int tid = threadIdx.x;
    const int m0 = blockIdx.x * 32;
    const int lane = tid & 63;
    const int w = tid >> 6;            // 0..7

    // ---- phase 0: stage h tile ----
    {
        const int row = tid >> 4, kb = (tid & 15) * 16;
        int gr = m0 + row; if (gr >= M) gr = M - 1;
        int4v v = *(const int4v*)((const char*)h + (size_t)gr * 256 + kb);
        *(int4v*)(lds + row * 256 + (kb ^ ((row & 7) << 4))) = v;
    }

    // ---- phase 1: concatenated gather ----
    {
        const int g = lane >> 4, li = lane & 15;
        const int* __restrict__ csr = csr_src + (size_t)g * NE;
        const char* hp = (const char*)h + li * 16;
        const int n0 = m0 + (w << 2);
        const int rsB = g * (NN + 1);

        auto rs = [&](int i) {
            int n = n0 + i; if (n > M) n = M;
            return row_start[rsB + n];
        };
        const int s0 = rs(0);
        int eb = rs(1), b1 = rs(2), b2 = rs(3), b3 = rs(4);
        const int tend = b3;

        int t = s0, sb = s0, cur = 0;
        f32x4 a0 = {0.f, 0.f, 0.f, 0.f}, a1 = {0.f, 0.f, 0.f, 0.f};

        const int cbase = g * 256 + li * 16;

#define EMIT_SEG()                                                                   \
        {                                                                            \
            const float inv = 1.0f / fmaxf((float)(eb - sb), 1.0f);                  \
            unsigned int p0 = (unsigned int)f2bf(inv * a0[0]) |                      \
                              ((unsigned int)f2bf(inv * a0[1]) << 16);               \
            unsigned int p1 = (unsigned int)f2bf(inv * a0[2]) |                      \
                              ((unsigned int)f2bf(inv * a0[3]) << 16);               \
            unsigned int p2 = (unsigned int)f2bf(inv * a1[0]) |                      \
                              ((unsigned int)f2bf(inv * a1[1]) << 16);               \
            unsigned int p3 = (unsigned int)f2bf(inv * a1[2]) |                      \
                              ((unsigned int)f2bf(inv * a1[3]) << 16);               \
            const int row = (w << 2) + cur;                                          \
            *(int4v*)(lds + 8192 + row * 1024 + (cbase ^ ((row & 7) << 4))) =        \
                (int4v){(int)p0, (int)p1, (int)p2, (int)p3};                         \
            a0 = (f32x4){0.f, 0.f, 0.f, 0.f};                                        \
            a1 = (f32x4){0.f, 0.f, 0.f, 0.f};                                        \
            sb = eb; eb = b1; b1 = b2; b2 = b3; ++cur;                               \
        }

        // pipeline prologue (once per wave)
        int sC = 0;
        int4v v0 = {0,0,0,0}, v1 = {0,0,0,0};
        {
            int sA = 0, sB = 0;
            if (t     < tend) sA = csr[t];
            if (t + 1 < tend) sB = csr[t + 1];
            if (t + 2 < tend) sC = csr[t + 2];
            if (t     < tend) v0 = *(const int4v*)(hp + (size_t)sA * 256);
            if (t + 1 < tend) v1 = *(const int4v*)(hp + (size_t)sB * 256);
        }

        while (__any(t < tend)) {
            // emit finished segments before consuming edge t
            while (cur < 4 && t >= eb) EMIT_SEG();
            const bool act = t < tend;
            const int4v vc = v0;
            v0 = v1;
            if (t + 2 < tend) v1 = *(const int4v*)(hp + (size_t)sC * 256);
            sC = (t + 3 < tend) ? csr[t + 3] : 0;
            if (act) {
                const unsigned int* vu = (const unsigned int*)&vc;
                a0[0] += bflo(vu[0]); a0[1] += bfhi(vu[0]);
                a0[2] += bflo(vu[1]); a0[3] += bfhi(vu[1]);
                a1[0] += bflo(vu[2]); a1[1] += bfhi(vu[2]);
                a1[2] += bflo(vu[3]); a1[3] += bfhi(vu[3]);
            }
            ++t;
        }
        while (cur < 4) EMIT_SEG();
#undef EMIT_SEG
    }
    __syncthreads();

    // ---- phase 2: GEMM; wave w owns output cols w*16..w*16+16 ----
    const int lr = lane & 15;
    const int lg = lane >> 4;
    const char* bB = (const char*)Bt + (size_t)(w * 16 + lr) * 1280;

    f32x4 acc[2];
    acc[0] = (f32x4){0.f, 0.f, 0.f, 0.f};
    acc[1] = (f32x4){0.f, 0.f, 0.f, 0.f};

#pragma unroll
    for (int kb = 0; kb < 20; ++kb) {
        const int kByte = kb * 64 + lg * 16;
        bf16x8 bfr = *(const bf16x8*)(bB + kByte);
#pragma unroll
        for (int mi = 0; mi < 2; mi++) {
            const int row = mi * 16 + lr;
            int off;
            if (kb < 4) off = row * 256 + (kByte ^ ((row & 7) << 4));
            else        off = 8192 + row * 1024 + ((kByte - 256) ^ ((row & 7) << 4));
            bf16x8 af = *(const bf16x8*)(lds + off);
            acc[mi] = __builtin_amdgcn_mfma_f32_16x16x32_bf16(af, bfr, acc[mi], 0, 0, 0);
        }
    }

    __syncthreads();                        // all A-reads done; reuse LDS as bounce

    if (MODE == 0) {
        // relu -> bf16 tile [32][256B] at lds[0..8192)
#pragma unroll
        for (int mi = 0; mi < 2; mi++) {
            const int col = w * 16 + lr;
#pragma unroll
            for (int j = 0; j < 4; j++) {
                const int row = mi * 16 + lg * 4 + j;
                *(unsigned short*)(lds + row * 256 + col * 2) =
                    f2bf(fmaxf(acc[mi][j], 0.f));
            }
        }
        __syncthreads();
        unsigned short* o = (unsigned short*)outp;
        const int row = tid >> 4, kb = (tid & 15) * 16;
        const int grow = m0 + row;
        if (grow < M)
            *(int4v*)((char*)o + (size_t)grow * 256 + kb) = *(const int4v*)(lds + row * 256 + kb);
    } else {
        // f32 tile [32][512B] at lds[0..16384)
#pragma unroll
        for (int mi = 0; mi < 2; mi++) {
            const int col = w * 16 + lr;
#pragma unroll
            for (int j = 0; j < 4; j++) {
                const int row = mi * 16 + lg * 4 + j;
                *(float*)(lds + row * 512 + col * 4) = acc[mi][j];
            }
        }
        __syncthreads();
        float* o = (float*)outp;
#pragma unroll
        for (int i = 0; i < 2; i++) {
            const int c = tid + i * 512;       // 1024 chunks of 16B
            const int row = c >> 5, o16 = (c & 31) * 16;
            const int grow = m0 + row;
            if (grow < M)
                *(int4v*)((char*)o + (size_t)grow * 512 + o16) = *(const int4v*)(lds + row * 512 + o16);
        }
    }
}

// ---------------- final gather (float4) ----------------

__global__ __launch_bounds__(256) void gather_out_kernel(const float* __restrict__ hOut,
                                                         const int* __restrict__ head,
                                                         const int* __restrict__ tail,
                                                         float* __restrict__ out) {
    const int gid = blockIdx.x * 256 + threadIdx.x;
    const int q = gid >> 5, c = gid & 31;
    if (q >= 2 * NQ || c >= 25) return;
    const int node = (q < NQ) ? head[q] : tail[q - NQ];
    f32x4 v = *(const f32x4*)(hOut + (size_t)node * 128 + c * 4);
    *(f32x4*)(out + (size_t)q * OD + c * 4) = v;
}

// ---------------- launch ----------------

extern "C" void kernel_launch(void* const* d_in, const int* in_sizes, int n_in,
                              void* d_out, int out_size, void* d_ws, size_t ws_size,
                              hipStream_t stream) {
    const float* feature = (const float*)d_in[0];
    const float* Wr_h    = (const float*)d_in[1];   // [2][4][128][128]
    const float* Ws_h    = (const float*)d_in[2];   // [2][128][128]
    const float* Wr_o    = (const float*)d_in[3];   // [4][128][100]
    const float* Ws_o    = (const float*)d_in[4];   // [128][100]
    const int* edge_src  = (const int*)d_in[5];
    const int* edge_dst  = (const int*)d_in[6];
    const int* head_idx  = (const int*)d_in[7];
    const int* tail_idx  = (const int*)d_in[8];
    float* out = (float*)d_out;

    char* ws = (char*)d_ws;
    size_t off = 0;
    auto alloc = [&](size_t bytes) -> void* {
        void* p = ws + off;
        off += (bytes + 255) & ~(size_t)255;
        return p;
    };
    unsigned short* hA   = (unsigned short*)alloc((size_t)NN * HD * 2);
    unsigned short* hB   = (unsigned short*)alloc((size_t)NN * HD * 2);
    float*          hOut = (float*)alloc((size_t)NN * 128 * 4);
    unsigned short* Wt   = (unsigned short*)alloc((size_t)3 * 128 * 640 * 2);
    int*            deg  = (int*)alloc((size_t)NR * NN * 4);
    int*            rowS = (int*)alloc((size_t)NR * (NN + 1) * 4);
    int*            curs = (int*)alloc((size_t)NR * NN * 4);
    int*            csrS = (int*)alloc((size_t)NR * NE * 4 + 64);
    int*            excl = (int*)alloc((size_t)NR * NN * 4);
    int*            bsum = (int*)alloc((size_t)NR * NB_SCAN * 4);
    (void)ws_size;

    // prep: zero deg, then merged {count_deg | conv_feat | prep_w}
    hipMemsetAsync(deg, 0, (size_t)NR * NN * 4, stream);
    prep_merged_kernel<<<NB_COUNT + NB_CONV + NB_PREPW, 256, 0, stream>>>(
        edge_dst, deg, feature, hA, Ws_h, Wr_h, Ws_o, Wr_o, Wt);
    scanA_kernel<<<NR * NB_SCAN, 256, 0, stream>>>(deg, excl, bsum);
    scanC_kernel<<<NR * NB_SCAN, 256, 0, stream>>>(excl, bsum, rowS, curs);
    fill_csr_kernel<<<NB_COUNT, 256, 0, stream>>>(edge_src, edge_dst, curs, csrS);

    const int fblocks = (NN + 31) / 32;   // 1563
    unsigned short* WtH0 = Wt;
    unsigned short* WtH1 = Wt + 128 * 640;
    unsigned short* WtO  = Wt + 2 * 128 * 640;

    fused_kernel<0><<<fblocks, 512, 0, stream>>>(hA, WtH0, rowS, csrS, hB, NN);
    fused_kernel<0><<<fblocks, 512, 0, stream>>>(hB, WtH1, rowS, csrS, hA, NN);
    fused_kernel<1><<<fblocks, 512, 0, stream>>>(hA, WtO,  rowS, csrS, hOut, NN);

    gather_out_kernel<<<(2 * NQ * 32 + 255) / 256, 256, 0, stream>>>(hOut, head_idx, tail_idx, out);
}

// Round 11
// 259.911 us; speedup vs baseline: 1.4776x; 1.0331x over previous
//
#include <hip/hip_runtime.h>
#include <hip/hip_bf16.h>

#define NN 50000     // nodes
#define NR 4         // relations
#define NE 160000    // edges per relation
#define HD 128       // hidden dim
#define OD 100       // out dim
#define NQ 8192      // queries
#define NB_SCAN 196  // 196*256 >= NN

// merged-prep region sizes (all exact multiples of 256)
#define NB_COUNT 2500   // NR*NE/256
#define NB_CONV  6250   // NN*HD/4/256
#define NB_PREPW 960    // 3*128*640/256

typedef __attribute__((ext_vector_type(8))) short bf16x8;
typedef __attribute__((ext_vector_type(4))) float f32x4;
typedef __attribute__((ext_vector_type(4))) int int4v;

static __device__ __forceinline__ unsigned short f2bf(float f) {
    union { float f; unsigned int u; } v; v.f = f;
    unsigned int u = v.u;
    unsigned int r = u + 0x7FFFu + ((u >> 16) & 1u);   // RNE
    return (unsigned short)(r >> 16);
}
static __device__ __forceinline__ float bflo(unsigned int v) {
    union { unsigned int u; float f; } x; x.u = v << 16; return x.f;
}
static __device__ __forceinline__ float bfhi(unsigned int v) {
    union { unsigned int u; float f; } x; x.u = v & 0xffff0000u; return x.f;
}

// ---------------- merged prep: count_deg | conv_feat | prep_w ----------------

__global__ __launch_bounds__(256) void prep_merged_kernel(
        const int* __restrict__ edge_dst, int* __restrict__ deg,
        const float* __restrict__ feature, unsigned short* __restrict__ h,
        const float* __restrict__ Ws_h, const float* __restrict__ Wr_h,
        const float* __restrict__ Ws_o, const float* __restrict__ Wr_o,
        unsigned short* __restrict__ Wt) {
    const int b = blockIdx.x;
    if (b < NB_COUNT) {
        const int i = b * 256 + threadIdx.x;            // < NR*NE exactly
        const int r = i / NE;
        atomicAdd(&deg[r * NN + edge_dst[i]], 1);
    } else if (b < NB_COUNT + NB_CONV) {
        const int i = ((b - NB_COUNT) * 256 + threadIdx.x) * 4;  // < NN*HD exactly
        h[i + 0] = f2bf(feature[i + 0]);
        h[i + 1] = f2bf(feature[i + 1]);
        h[i + 2] = f2bf(feature[i + 2]);
        h[i + 3] = f2bf(feature[i + 3]);
    } else {
        const int idx = (b - NB_COUNT - NB_CONV) * 256 + threadIdx.x;  // < 3*128*640
        const int l = idx / (128 * 640);
        const int rem = idx % (128 * 640);
        const int c = rem / 640;
        const int k = rem % 640;
        float v = 0.0f;
        if (l < 2) {
            if (k < HD) v = Ws_h[(l * HD + k) * HD + c];
            else {
                int r = (k - HD) >> 7, kk = (k - HD) & 127;
                v = Wr_h[((l * NR + r) * HD + kk) * HD + c];
            }
        } else if (c < OD) {
            if (k < HD) v = Ws_o[k * OD + c];
            else {
                int r = (k - HD) >> 7, kk = (k - HD) & 127;
                v = Wr_o[(r * HD + kk) * OD + c];
            }
        }
        Wt[idx] = f2bf(v);
    }
}

// ---------------- scan ----------------

__global__ __launch_bounds__(256) void scanA_kernel(const int* __restrict__ deg,
                                                    int* __restrict__ excl,
                                                    int* __restrict__ bsum) {
    const int r = blockIdx.x / NB_SCAN;
    const int b = blockIdx.x % NB_SCAN;
    const int tid = threadIdx.x;
    const int idx = b * 256 + tid;
    int v = (idx < NN) ? deg[r * NN + idx] : 0;
    __shared__ int buf[256];
    buf[tid] = v; __syncthreads();
    int sum = v;
    for (int off = 1; off < 256; off <<= 1) {
        int t = (tid >= off) ? buf[tid - off] : 0;
        __syncthreads();
        sum += t; buf[tid] = sum;
        __syncthreads();
    }
    if (idx < NN) excl[r * NN + idx] = sum - v;
    if (tid == 255) bsum[r * NB_SCAN + b] = sum;
}

// scanC with inlined chunk-prefix reduction (replaces scanB)
__global__ __launch_bounds__(256) void scanC_kernel(const int* __restrict__ excl,
                                                    const int* __restrict__ bsum,
                                                    int* __restrict__ row_start,
                                                    int* __restrict__ cursor) {
    const int r = blockIdx.x / NB_SCAN;
    const int b = blockIdx.x % NB_SCAN;
    const int tid = threadIdx.x;
    __shared__ int buf[256];
    // prefix = sum of bsum[r][0..b-1]  (b <= 195 < 256)
    buf[tid] = (tid < b) ? bsum[r * NB_SCAN + tid] : 0;
    __syncthreads();
    for (int off = 128; off > 0; off >>= 1) {
        if (tid < off) buf[tid] += buf[tid + off];
        __syncthreads();
    }
    const int prefix = buf[0];
    const int idx = b * 256 + tid;
    if (idx < NN) {
        int v = excl[r * NN + idx] + prefix;
        row_start[r * (NN + 1) + idx] = v;
        cursor[r * NN + idx] = v;
    }
    if (b == 0 && tid == 0) row_start[r * (NN + 1) + NN] = NE;
}

__global__ __launch_bounds__(256) void fill_csr_kernel(const int* __restrict__ edge_src,
                                                       const int* __restrict__ edge_dst,
                                                       int* __restrict__ cursor,
                                                       int* __restrict__ csr_src) {
    const int i = blockIdx.x * 256 + threadIdx.x;     // < NR*NE exactly
    const int r = i / NE;
    const int dst = edge_dst[i];
    const int pos = atomicAdd(&cursor[r * NN + dst], 1);
    csr_src[r * NE + pos] = edge_src[i];
}

// ---------------- fused: 8-slot batched reg-gather + GEMM ----------------
// Block = 512 thr (8 waves), 32 nodes. LDS 40KB: [0,8192) hT ; [8192,40960) agg.
// Phase 0: stage h tile [32][256B] -> LDS (swizzled), 1 x 16B per thread.
// Phase 1: wave w handles nodes 4w..4w+3; lane-group g (16 lanes x 16B = full
//          256B h row) = relation g. Per node: all 8 slot indices loaded
//          (guarded, independent), then all 8 h-rows (guarded, independent)
//          -> 8-deep MLP, no dependent stepping; empty slots zero-filled and
//          accumulated unconditionally. Rare tail loop for deg > 8 (P~0.5%).
//          Scale by 1/(e-s); one swizzled ds_write_b128 per node. No atomics.
// Phase 2: GEMM [hT | agg](32x640) @ Wt(128x640)^T. Wave w owns 16 cols;
//          A from LDS (XOR swizzle), B direct from global Wt (L2-resident);
//          20 K-steps, no barriers in loop.
// MODE 0: relu + bf16 out via LDS bounce. MODE 1: f32 out via LDS bounce.

template<int MODE>
__global__ __launch_bounds__(512, 8)
void fused_kernel(const unsigned short* __restrict__ h,
                  const unsigned short* __restrict__ Bt,
                  const int* __restrict__ row_start,
                  const int* __restrict__ csr_src,
                  void* __restrict__ outp, int M) {
    __shared__ __align__(16) char lds[40960];   // [0,8192) hT ; [8192,40960) agg
    const int tid = threadIdx.x;
    const int m0 = blockIdx.x * 32;
    const int lane = tid & 63;
    const int w = tid >> 6;            // 0..7

    // ---- phase 0: stage h tile ----
    {
        const int row = tid >> 4, kb = (tid & 15) * 16;
        int gr = m0 + row; if (gr >= M) gr = M - 1;
        int4v v = *(const int4v*)((const char*)h + (size_t)gr * 256 + kb);
        *(int4v*)(lds + row * 256 + (kb ^ ((row & 7) << 4))) = v;
    }

    // ---- phase 1: 8-slot batched gather ----
    {
        const int g = lane >> 4, li = lane & 15;
        const int* __restrict__ csr = csr_src + (size_t)g * NE;
        const char* hp = (const char*)h + li * 16;
        const int n0 = m0 + (w << 2);
        const int rsB = g * (NN + 1);

        int bnd[5];
#pragma unroll
        for (int i = 0; i < 5; i++) {
            int n = n0 + i; if (n > M) n = M;
            bnd[i] = row_start[rsB + n];
        }

#pragma unroll 1
        for (int i = 0; i < 4; ++i) {
            const int s = bnd[i], e = bnd[i + 1];

            // batch 1: all 8 slot indices (independent, guarded)
            int sj[8];
#pragma unroll
            for (int j = 0; j < 8; j++) sj[j] = (s + j < e) ? csr[s + j] : 0;

            // batch 2: all 8 rows (independent, guarded; zero-filled if empty)
            int4v vj[8];
#pragma unroll
            for (int j = 0; j < 8; j++) {
                if (s + j < e) vj[j] = *(const int4v*)(hp + (size_t)sj[j] * 256);
                else           vj[j] = (int4v){0, 0, 0, 0};
            }

            f32x4 a0 = {0.f, 0.f, 0.f, 0.f}, a1 = {0.f, 0.f, 0.f, 0.f};
#pragma unroll
            for (int j = 0; j < 8; j++) {
                const unsigned int* vu = (const unsigned int*)&vj[j];
                a0[0] += bflo(vu[0]); a0[1] += bfhi(vu[0]);
                a0[2] += bflo(vu[1]); a0[3] += bfhi(vu[1]);
                a1[0] += bflo(vu[2]); a1[1] += bfhi(vu[2]);
                a1[2] += bflo(vu[3]); a1[3] += bfhi(vu[3]);
            }

            // rare tail: deg > 8
            for (int t = s + 8; t < e; ++t) {
                const int src = csr[t];
                const int4v v = *(const int4v*)(hp + (size_t)src * 256);
                const unsigned int* vu = (const unsigned int*)&v;
                a0[0] += bflo(vu[0]); a0[1] += bfhi(vu[0]);
                a0[2] += bflo(vu[1]); a0[3] += bfhi(vu[1]);
                a1[0] += bflo(vu[2]); a1[1] += bfhi(vu[2]);
                a1[2] += bflo(vu[3]); a1[3] += bfhi(vu[3]);
            }

            const float inv = 1.0f / fmaxf((float)(e - s), 1.0f);
            unsigned int p0 = (unsigned int)f2bf(inv * a0[0]) | ((unsigned int)f2bf(inv * a0[1]) << 16);
            unsigned int p1 = (unsigned int)f2bf(inv * a0[2]) | ((unsigned int)f2bf(inv * a0[3]) << 16);
            unsigned int p2 = (unsigned int)f2bf(inv * a1[0]) | ((unsigned int)f2bf(inv * a1[1]) << 16);
            unsigned int p3 = (unsigned int)f2bf(inv * a1[2]) | ((unsigned int)f2bf(inv * a1[3]) << 16);
            const int row = (w << 2) + i;
            const int cb = g * 256 + li * 16;
            *(int4v*)(lds + 8192 + row * 1024 + (cb ^ ((row & 7) << 4))) =
                (int4v){(int)p0, (int)p1, (int)p2, (int)p3};
        }
    }
    __syncthreads();

    // ---- phase 2: GEMM; wave w owns output cols w*16..w*16+16 ----
    const int lr = lane & 15;
    const int lg = lane >> 4;
    const char* bB = (const char*)Bt + (size_t)(w * 16 + lr) * 1280;

    f32x4 acc[2];
    acc[0] = (f32x4){0.f, 0.f, 0.f, 0.f};
    acc[1] = (f32x4){0.f, 0.f, 0.f, 0.f};

#pragma unroll
    for (int kb = 0; kb < 20; ++kb) {
        const int kByte = kb * 64 + lg * 16;
        bf16x8 bfr = *(const bf16x8*)(bB + kByte);
#pragma unroll
        for (int mi = 0; mi < 2; mi++) {
            const int row = mi * 16 + lr;
            int off;
            if (kb < 4) off = row * 256 + (kByte ^ ((row & 7) << 4));
            else        off = 8192 + row * 1024 + ((kByte - 256) ^ ((row & 7) << 4));
            bf16x8 af = *(const bf16x8*)(lds + off);
            acc[mi] = __builtin_amdgcn_mfma_f32_16x16x32_bf16(af, bfr, acc[mi], 0, 0, 0);
        }
    }

    __syncthreads();                        // all A-reads done; reuse LDS as bounce

    if (MODE == 0) {
        // relu -> bf16 tile [32][256B] at lds[0..8192)
#pragma unroll
        for (int mi = 0; mi < 2; mi++) {
            const int col = w * 16 + lr;
#pragma unroll
            for (int j = 0; j < 4; j++) {
                const int row = mi * 16 + lg * 4 + j;
                *(unsigned short*)(lds + row * 256 + col * 2) =
                    f2bf(fmaxf(acc[mi][j], 0.f));
            }
        }
        __syncthreads();
        unsigned short* o = (unsigned short*)outp;
        const int row = tid >> 4, kb = (tid & 15) * 16;
        const int grow = m0 + row;
        if (grow < M)
            *(int4v*)((char*)o + (size_t)grow * 256 + kb) = *(const int4v*)(lds + row * 256 + kb);
    } else {
        // f32 tile [32][512B] at lds[0..16384)
#pragma unroll
        for (int mi = 0; mi < 2; mi++) {
            const int col = w * 16 + lr;
#pragma unroll
            for (int j = 0; j < 4; j++) {
                const int row = mi * 16 + lg * 4 + j;
                *(float*)(lds + row * 512 + col * 4) = acc[mi][j];
            }
        }
        __syncthreads();
        float* o = (float*)outp;
#pragma unroll
        for (int i = 0; i < 2; i++) {
            const int c = tid + i * 512;       // 1024 chunks of 16B
            const int row = c >> 5, o16 = (c & 31) * 16;
            const int grow = m0 + row;
            if (grow < M)
                *(int4v*)((char*)o + (size_t)grow * 512 + o16) = *(const int4v*)(lds + row * 512 + o16);
        }
    }
}

// ---------------- final gather (float4) ----------------

__global__ __launch_bounds__(256) void gather_out_kernel(const float* __restrict__ hOut,
                                                         const int* __restrict__ head,
                                                         const int* __restrict__ tail,
                                                         float* __restrict__ out) {
    const int gid = blockIdx.x * 256 + threadIdx.x;
    const int q = gid >> 5, c = gid & 31;
    if (q >= 2 * NQ || c >= 25) return;
    const int node = (q < NQ) ? head[q] : tail[q - NQ];
    f32x4 v = *(const f32x4*)(hOut + (size_t)node * 128 + c * 4);
    *(f32x4*)(out + (size_t)q * OD + c * 4) = v;
}

// ---------------- launch ----------------

extern "C" void kernel_launch(void* const* d_in, const int* in_sizes, int n_in,
                              void* d_out, int out_size, void* d_ws, size_t ws_size,
                              hipStream_t stream) {
    const float* feature = (const float*)d_in[0];
    const float* Wr_h    = (const float*)d_in[1];   // [2][4][128][128]
    const float* Ws_h    = (const float*)d_in[2];   // [2][128][128]
    const float* Wr_o    = (const float*)d_in[3];   // [4][128][100]
    const float* Ws_o    = (const float*)d_in[4];   // [128][100]
    const int* edge_src  = (const int*)d_in[5];
    const int* edge_dst  = (const int*)d_in[6];
    const int* head_idx  = (const int*)d_in[7];
    const int* tail_idx  = (const int*)d_in[8];
    float* out = (float*)d_out;

    char* ws = (char*)d_ws;
    size_t off = 0;
    auto alloc = [&](size_t bytes) -> void* {
        void* p = ws + off;
        off += (bytes + 255) & ~(size_t)255;
        return p;
    };
    unsigned short* hA   = (unsigned short*)alloc((size_t)NN * HD * 2);
    unsigned short* hB   = (unsigned short*)alloc((size_t)NN * HD * 2);
    float*          hOut = (float*)alloc((size_t)NN * 128 * 4);
    unsigned short* Wt   = (unsigned short*)alloc((size_t)3 * 128 * 640 * 2);
    int*            deg  = (int*)alloc((size_t)NR * NN * 4);
    int*            rowS = (int*)alloc((size_t)NR * (NN + 1) * 4);
    int*            curs = (int*)alloc((size_t)NR * NN * 4);
    int*            csrS = (int*)alloc((size_t)NR * NE * 4 + 64);
    int*            excl = (int*)alloc((size_t)NR * NN * 4);
    int*            bsum = (int*)alloc((size_t)NR * NB_SCAN * 4);
    (void)ws_size;

    // prep: zero deg, then merged {count_deg | conv_feat | prep_w}
    hipMemsetAsync(deg, 0, (size_t)NR * NN * 4, stream);
    prep_merged_kernel<<<NB_COUNT + NB_CONV + NB_PREPW, 256, 0, stream>>>(
        edge_dst, deg, feature, hA, Ws_h, Wr_h, Ws_o, Wr_o, Wt);
    scanA_kernel<<<NR * NB_SCAN, 256, 0, stream>>>(deg, excl, bsum);
    scanC_kernel<<<NR * NB_SCAN, 256, 0, stream>>>(excl, bsum, rowS, curs);
    fill_csr_kernel<<<NB_COUNT, 256, 0, stream>>>(edge_src, edge_dst, curs, csrS);

    const int fblocks = (NN + 31) / 32;   // 1563
    unsigned short* WtH0 = Wt;
    unsigned short* WtH1 = Wt + 128 * 640;
    unsigned short* WtO  = Wt + 2 * 128 * 640;

    fused_kernel<0><<<fblocks, 512, 0, stream>>>(hA, WtH0, rowS, csrS, hB, NN);
    fused_kernel<0><<<fblocks, 512, 0, stream>>>(hB, WtH1, rowS, csrS, hA, NN);
    fused_kernel<1><<<fblocks, 512, 0, stream>>>(hA, WtO,  rowS, csrS, hOut, NN);

    gather_out_kernel<<<(2 * NQ * 32 + 255) / 256, 256, 0, stream>>>(hOut, head_idx, tail_idx, out);
}

// Round 12
// 251.614 us; speedup vs baseline: 1.5263x; 1.0330x over previous
//
#include <hip/hip_runtime.h>
#include <hip/hip_bf16.h>

#define NN 50000     // nodes
#define NR 4         // relations
#define NE 160000    // edges per relation
#define HD 128       // hidden dim
#define OD 100       // out dim
#define NQ 8192      // queries
#define NB_SCAN 196  // 196*256 >= NN

// merged-prep region sizes (all exact multiples of 256)
#define NB_COUNT 2500   // NR*NE/256
#define NB_CONV  6250   // NN*HD/4/256
#define NB_PREPW 960    // 3*128*640/256

typedef __attribute__((ext_vector_type(8))) short bf16x8;
typedef __attribute__((ext_vector_type(4))) float f32x4;
typedef __attribute__((ext_vector_type(2))) float f32x2;
typedef __attribute__((ext_vector_type(4))) int int4v;

static __device__ __forceinline__ unsigned short f2bf(float f) {
    union { float f; unsigned int u; } v; v.f = f;
    unsigned int u = v.u;
    unsigned int r = u + 0x7FFFu + ((u >> 16) & 1u);   // RNE
    return (unsigned short)(r >> 16);
}
static __device__ __forceinline__ float bflo(unsigned int v) {
    union { unsigned int u; float f; } x; x.u = v << 16; return x.f;
}
static __device__ __forceinline__ float bfhi(unsigned int v) {
    union { unsigned int u; float f; } x; x.u = v & 0xffff0000u; return x.f;
}

// ---------------- merged prep: count_deg | conv_feat | prep_w ----------------

__global__ __launch_bounds__(256) void prep_merged_kernel(
        const int* __restrict__ edge_dst, int* __restrict__ deg,
        const float* __restrict__ feature, unsigned short* __restrict__ h,
        const float* __restrict__ Ws_h, const float* __restrict__ Wr_h,
        const float* __restrict__ Ws_o, const float* __restrict__ Wr_o,
        unsigned short* __restrict__ Wt) {
    const int b = blockIdx.x;
    if (b < NB_COUNT) {
        const int i = b * 256 + threadIdx.x;            // < NR*NE exactly
        const int r = i / NE;
        atomicAdd(&deg[r * NN + edge_dst[i]], 1);
    } else if (b < NB_COUNT + NB_CONV) {
        const int i = ((b - NB_COUNT) * 256 + threadIdx.x) * 4;  // < NN*HD exactly
        h[i + 0] = f2bf(feature[i + 0]);
        h[i + 1] = f2bf(feature[i + 1]);
        h[i + 2] = f2bf(feature[i + 2]);
        h[i + 3] = f2bf(feature[i + 3]);
    } else {
        const int idx = (b - NB_COUNT - NB_CONV) * 256 + threadIdx.x;  // < 3*128*640
        const int l = idx / (128 * 640);
        const int rem = idx % (128 * 640);
        const int c = rem / 640;
        const int k = rem % 640;
        float v = 0.0f;
        if (l < 2) {
            if (k < HD) v = Ws_h[(l * HD + k) * HD + c];
            else {
                int r = (k - HD) >> 7, kk = (k - HD) & 127;
                v = Wr_h[((l * NR + r) * HD + kk) * HD + c];
            }
        } else if (c < OD) {
            if (k < HD) v = Ws_o[k * OD + c];
            else {
                int r = (k - HD) >> 7, kk = (k - HD) & 127;
                v = Wr_o[(r * HD + kk) * OD + c];
            }
        }
        Wt[idx] = f2bf(v);
    }
}

// ---------------- scan ----------------

__global__ __launch_bounds__(256) void scanA_kernel(const int* __restrict__ deg,
                                                    int* __restrict__ excl,
                                                    int* __restrict__ bsum) {
    const int r = blockIdx.x / NB_SCAN;
    const int b = blockIdx.x % NB_SCAN;
    const int tid = threadIdx.x;
    const int idx = b * 256 + tid;
    int v = (idx < NN) ? deg[r * NN + idx] : 0;
    __shared__ int buf[256];
    buf[tid] = v; __syncthreads();
    int sum = v;
    for (int off = 1; off < 256; off <<= 1) {
        int t = (tid >= off) ? buf[tid - off] : 0;
        __syncthreads();
        sum += t; buf[tid] = sum;
        __syncthreads();
    }
    if (idx < NN) excl[r * NN + idx] = sum - v;
    if (tid == 255) bsum[r * NB_SCAN + b] = sum;
}

// scanC with inlined chunk-prefix reduction (replaces scanB)
__global__ __launch_bounds__(256) void scanC_kernel(const int* __restrict__ excl,
                                                    const int* __restrict__ bsum,
                                                    int* __restrict__ row_start,
                                                    int* __restrict__ cursor) {
    const int r = blockIdx.x / NB_SCAN;
    const int b = blockIdx.x % NB_SCAN;
    const int tid = threadIdx.x;
    __shared__ int buf[256];
    // prefix = sum of bsum[r][0..b-1]  (b <= 195 < 256)
    buf[tid] = (tid < b) ? bsum[r * NB_SCAN + tid] : 0;
    __syncthreads();
    for (int off = 128; off > 0; off >>= 1) {
        if (tid < off) buf[tid] += buf[tid + off];
        __syncthreads();
    }
    const int prefix = buf[0];
    const int idx = b * 256 + tid;
    if (idx < NN) {
        int v = excl[r * NN + idx] + prefix;
        row_start[r * (NN + 1) + idx] = v;
        cursor[r * NN + idx] = v;
    }
    if (b == 0 && tid == 0) row_start[r * (NN + 1) + NN] = NE;
}

__global__ __launch_bounds__(256) void fill_csr_kernel(const int* __restrict__ edge_src,
                                                       const int* __restrict__ edge_dst,
                                                       int* __restrict__ cursor,
                                                       int* __restrict__ csr_src) {
    const int i = blockIdx.x * 256 + threadIdx.x;     // < NR*NE exactly
    const int r = i / NE;
    const int dst = edge_dst[i];
    const int pos = atomicAdd(&cursor[r * NN + dst], 1);
    csr_src[r * NE + pos] = edge_src[i];
}

// ---------------- fused: 8-slot batched reg-gather + GEMM ----------------
// Block = 512 thr (8 waves), 32 nodes. LDS 40KB: [0,8192) hT ; [8192,40960) agg.
// Phase 0: stage h tile [32][256B] -> LDS (swizzled), 1 x 16B per thread.
// Phase 1: wave w handles nodes 4w..4w+3; lane-group g (16 lanes x 16B = full
//          256B h row) = relation g. Per node: 8 slot indices + 8 h-rows
//          batched (guarded, independent, 8-deep MLP); packed f32x2
//          accumulation (v_pk_add_f32); rare tail for deg > 8.
//          Scale by 1/(e-s); one swizzled ds_write_b128 per node. No atomics.
// Phase 2: GEMM [hT | agg](32x640) @ Wt(128x640)^T. Wave w owns 16 cols;
//          B frags kb<4 prefetched pre-barrier; A from LDS (XOR swizzle);
//          20 K-steps, setprio(1) around the MFMA loop.
// Epilogues: XOR-swizzled LDS bounce (conflict-free), coalesced 16B stores.

template<int MODE>
__global__ __launch_bounds__(512, 8)
void fused_kernel(const unsigned short* __restrict__ h,
                  const unsigned short* __restrict__ Bt,
                  const int* __restrict__ row_start,
                  const int* __restrict__ csr_src,
                  void* __restrict__ outp, int M) {
    __shared__ __align__(16) char lds[40960];   // [0,8192) hT ; [8192,40960) agg
    const int tid = threadIdx.x;
    const int m0 = blockIdx.x * 32;
    const int lane = tid & 63;
    const int w = tid >> 6;            // 0..7

    // ---- phase 0: stage h tile ----
    {
        const int row = tid >> 4, kb = (tid & 15) * 16;
        int gr = m0 + row; if (gr >= M) gr = M - 1;
        int4v v = *(const int4v*)((const char*)h + (size_t)gr * 256 + kb);
        *(int4v*)(lds + row * 256 + (kb ^ ((row & 7) << 4))) = v;
    }

    // ---- phase 1: 8-slot batched gather (packed f32x2 accumulate) ----
    {
        const int g = lane >> 4, li = lane & 15;
        const int* __restrict__ csr = csr_src + (size_t)g * NE;
        const char* hp = (const char*)h + li * 16;
        const int n0 = m0 + (w << 2);
        const int rsB = g * (NN + 1);

        int bnd[5];
#pragma unroll
        for (int i = 0; i < 5; i++) {
            int n = n0 + i; if (n > M) n = M;
            bnd[i] = row_start[rsB + n];
        }

#pragma unroll 1
        for (int i = 0; i < 4; ++i) {
            const int s = bnd[i], e = bnd[i + 1];

            // batch 1: all 8 slot indices (independent, guarded)
            int sj[8];
#pragma unroll
            for (int j = 0; j < 8; j++) sj[j] = (s + j < e) ? csr[s + j] : 0;

            // batch 2: all 8 rows (independent, guarded; zero-filled if empty)
            int4v vj[8];
#pragma unroll
            for (int j = 0; j < 8; j++) {
                if (s + j < e) vj[j] = *(const int4v*)(hp + (size_t)sj[j] * 256);
                else           vj[j] = (int4v){0, 0, 0, 0};
            }

            f32x2 c0 = {0.f, 0.f}, c1 = {0.f, 0.f}, c2 = {0.f, 0.f}, c3 = {0.f, 0.f};
#pragma unroll
            for (int j = 0; j < 8; j++) {
                const unsigned int* vu = (const unsigned int*)&vj[j];
                c0 += (f32x2){bflo(vu[0]), bfhi(vu[0])};
                c1 += (f32x2){bflo(vu[1]), bfhi(vu[1])};
                c2 += (f32x2){bflo(vu[2]), bfhi(vu[2])};
                c3 += (f32x2){bflo(vu[3]), bfhi(vu[3])};
            }

            // rare tail: deg > 8
            for (int t = s + 8; t < e; ++t) {
                const int src = csr[t];
                const int4v v = *(const int4v*)(hp + (size_t)src * 256);
                const unsigned int* vu = (const unsigned int*)&v;
                c0 += (f32x2){bflo(vu[0]), bfhi(vu[0])};
                c1 += (f32x2){bflo(vu[1]), bfhi(vu[1])};
                c2 += (f32x2){bflo(vu[2]), bfhi(vu[2])};
                c3 += (f32x2){bflo(vu[3]), bfhi(vu[3])};
            }

            const float inv = 1.0f / fmaxf((float)(e - s), 1.0f);
            unsigned int p0 = (unsigned int)f2bf(inv * c0[0]) | ((unsigned int)f2bf(inv * c0[1]) << 16);
            unsigned int p1 = (unsigned int)f2bf(inv * c1[0]) | ((unsigned int)f2bf(inv * c1[1]) << 16);
            unsigned int p2 = (unsigned int)f2bf(inv * c2[0]) | ((unsigned int)f2bf(inv * c2[1]) << 16);
            unsigned int p3 = (unsigned int)f2bf(inv * c3[0]) | ((unsigned int)f2bf(inv * c3[1]) << 16);
            const int row = (w << 2) + i;
            const int cb = g * 256 + li * 16;
            *(int4v*)(lds + 8192 + row * 1024 + (cb ^ ((row & 7) << 4))) =
                (int4v){(int)p0, (int)p1, (int)p2, (int)p3};
        }
    }

    // ---- B-fragment prefetch for kb=0..3 (independent of LDS; hides under barrier) ----
    const int lr = lane & 15;
    const int lg = lane >> 4;
    const char* bB = (const char*)Bt + (size_t)(w * 16 + lr) * 1280;
    bf16x8 bpre[4];
#pragma unroll
    for (int kb = 0; kb < 4; kb++)
        bpre[kb] = *(const bf16x8*)(bB + kb * 64 + lg * 16);

    __syncthreads();

    // ---- phase 2: GEMM; wave w owns output cols w*16..w*16+16 ----
    f32x4 acc[2];
    acc[0] = (f32x4){0.f, 0.f, 0.f, 0.f};
    acc[1] = (f32x4){0.f, 0.f, 0.f, 0.f};

    __builtin_amdgcn_s_setprio(1);
#pragma unroll
    for (int kb = 0; kb < 20; ++kb) {
        const int kByte = kb * 64 + lg * 16;
        bf16x8 bfr = (kb < 4) ? bpre[kb] : *(const bf16x8*)(bB + kByte);
#pragma unroll
        for (int mi = 0; mi < 2; mi++) {
            const int row = mi * 16 + lr;
            int off;
            if (kb < 4) off = row * 256 + (kByte ^ ((row & 7) << 4));
            else        off = 8192 + row * 1024 + ((kByte - 256) ^ ((row & 7) << 4));
            bf16x8 af = *(const bf16x8*)(lds + off);
            acc[mi] = __builtin_amdgcn_mfma_f32_16x16x32_bf16(af, bfr, acc[mi], 0, 0, 0);
        }
    }
    __builtin_amdgcn_s_setprio(0);

    __syncthreads();                        // all A-reads done; reuse LDS as bounce

    if (MODE == 0) {
        // relu -> bf16 tile [32][256B] at lds[0..8192), XOR-swizzled rows
#pragma unroll
        for (int mi = 0; mi < 2; mi++) {
            const int col = w * 16 + lr;
#pragma unroll
            for (int j = 0; j < 4; j++) {
                const int row = mi * 16 + lg * 4 + j;
                *(unsigned short*)(lds + row * 256 + ((col * 2) ^ ((row & 7) << 4))) =
                    f2bf(fmaxf(acc[mi][j], 0.f));
            }
        }
        __syncthreads();
        unsigned short* o = (unsigned short*)outp;
        const int row = tid >> 4, kb = (tid & 15) * 16;
        const int grow = m0 + row;
        if (grow < M)
            *(int4v*)((char*)o + (size_t)grow * 256 + kb) =
                *(const int4v*)(lds + row * 256 + (kb ^ ((row & 7) << 4)));
    } else {
        // f32 tile [32][512B] at lds[0..16384), XOR-swizzled rows
#pragma unroll
        for (int mi = 0; mi < 2; mi++) {
            const int col = w * 16 + lr;
#pragma unroll
            for (int j = 0; j < 4; j++) {
                const int row = mi * 16 + lg * 4 + j;
                *(float*)(lds + row * 512 + ((col * 4) ^ ((row & 7) << 4))) = acc[mi][j];
            }
        }
        __syncthreads();
        float* o = (float*)outp;
#pragma unroll
        for (int i = 0; i < 2; i++) {
            const int c = tid + i * 512;       // 1024 chunks of 16B
            const int row = c >> 5, o16 = (c & 31) * 16;
            const int grow = m0 + row;
            if (grow < M)
                *(int4v*)((char*)o + (size_t)grow * 512 + o16) =
                    *(const int4v*)(lds + row * 512 + (o16 ^ ((row & 7) << 4)));
        }
    }
}

// ---------------- final gather (float4) ----------------

__global__ __launch_bounds__(256) void gather_out_kernel(const float* __restrict__ hOut,
                                                         const int* __restrict__ head,
                                                         const int* __restrict__ tail,
                                                         float* __restrict__ out) {
    const int gid = blockIdx.x * 256 + threadIdx.x;
    const int q = gid >> 5, c = gid & 31;
    if (q >= 2 * NQ || c >= 25) return;
    const int node = (q < NQ) ? head[q] : tail[q - NQ];
    f32x4 v = *(const f32x4*)(hOut + (size_t)node * 128 + c * 4);
    *(f32x4*)(out + (size_t)q * OD + c * 4) = v;
}

// ---------------- launch ----------------

extern "C" void kernel_launch(void* const* d_in, const int* in_sizes, int n_in,
                              void* d_out, int out_size, void* d_ws, size_t ws_size,
                              hipStream_t stream) {
    const float* feature = (const float*)d_in[0];
    const float* Wr_h    = (const float*)d_in[1];   // [2][4][128][128]
    const float* Ws_h    = (const float*)d_in[2];   // [2][128][128]
    const float* Wr_o    = (const float*)d_in[3];   // [4][128][100]
    const float* Ws_o    = (const float*)d_in[4];   // [128][100]
    const int* edge_src  = (const int*)d_in[5];
    const int* edge_dst  = (const int*)d_in[6];
    const int* head_idx  = (const int*)d_in[7];
    const int* tail_idx  = (const int*)d_in[8];
    float* out = (float*)d_out;

    char* ws = (char*)d_ws;
    size_t off = 0;
    auto alloc = [&](size_t bytes) -> void* {
        void* p = ws + off;
        off += (bytes + 255) & ~(size_t)255;
        return p;
    };
    unsigned short* hA   = (unsigned short*)alloc((size_t)NN * HD * 2);
    unsigned short* hB   = (unsigned short*)alloc((size_t)NN * HD * 2);
    float*          hOut = (float*)alloc((size_t)NN * 128 * 4);
    unsigned short* Wt   = (unsigned short*)alloc((size_t)3 * 128 * 640 * 2);
    int*            deg  = (int*)alloc((size_t)NR * NN * 4);
    int*            rowS = (int*)alloc((size_t)NR * (NN + 1) * 4);
    int*            curs = (int*)alloc((size_t)NR * NN * 4);
    int*            csrS = (int*)alloc((size_t)NR * NE * 4 + 64);
    int*            excl = (int*)alloc((size_t)NR * NN * 4);
    int*            bsum = (int*)alloc((size_t)NR * NB_SCAN * 4);
    (void)ws_size;

    // prep: zero deg, then merged {count_deg | conv_feat | prep_w}
    hipMemsetAsync(deg, 0, (size_t)NR * NN * 4, stream);
    prep_merged_kernel<<<NB_COUNT + NB_CONV + NB_PREPW, 256, 0, stream>>>(
        edge_dst, deg, feature, hA, Ws_h, Wr_h, Ws_o, Wr_o, Wt);
    scanA_kernel<<<NR * NB_SCAN, 256, 0, stream>>>(deg, excl, bsum);
    scanC_kernel<<<NR * NB_SCAN, 256, 0, stream>>>(excl, bsum, rowS, curs);
    fill_csr_kernel<<<NB_COUNT, 256, 0, stream>>>(edge_src, edge_dst, curs, csrS);

    const int fblocks = (NN + 31) / 32;   // 1563
    unsigned short* WtH0 = Wt;
    unsigned short* WtH1 = Wt + 128 * 640;
    unsigned short* WtO  = Wt + 2 * 128 * 640;

    fused_kernel<0><<<fblocks, 512, 0, stream>>>(hA, WtH0, rowS, csrS, hB, NN);
    fused_kernel<0><<<fblocks, 512, 0, stream>>>(hB, WtH1, rowS, csrS, hA, NN);
    fused_kernel<1><<<fblocks, 512, 0, stream>>>(hA, WtO,  rowS, csrS, hOut, NN);

    gather_out_kernel<<<(2 * NQ * 32 + 255) / 256, 256, 0, stream>>>(hOut, head_idx, tail_idx, out);
}